// Round 4
// baseline (442.561 us; speedup 1.0000x reference)
//
#include <hip/hip_runtime.h>
#include <hip/hip_bf16.h>

typedef unsigned short u16;
typedef __attribute__((ext_vector_type(4))) float f32x4;
typedef __attribute__((ext_vector_type(4))) unsigned int u32x4;
typedef __attribute__((ext_vector_type(4))) unsigned short u16x4;
typedef __attribute__((ext_vector_type(8))) __bf16 bf16x8;

__device__ inline u16 f2u(float f) {
    __hip_bfloat16 b = __float2bfloat16(f);
    return *reinterpret_cast<u16*>(&b);
}
__device__ inline f32x4 mfma16(bf16x8 a, bf16x8 b, f32x4 c) {
    return __builtin_amdgcn_mfma_f32_16x16x32_bf16(a, b, c, 0, 0, 0);
}
__device__ inline void gload_lds16(const u16* g, u16* l) {
    __builtin_amdgcn_global_load_lds(
        (const __attribute__((address_space(1))) unsigned int*)g,
        (__attribute__((address_space(3))) unsigned int*)l, 16, 0, 0);
}

// ---------------------------------------------------------------------------
// m97-style 128x128 MFMA GEMM, BK=64, global_load_lds staging, XOR chunk
// swizzle. A: [M,K] row-major (ld=K). B: [N,K] row-major (ld=K).
// Batched via blockIdx.z with strideA/strideB (0 = shared operand).
//  OUT_MODE 0: Out[row*ldOut + col]
//  OUT_MODE 1: head layout   [bh][l][d]: b=row>>logL, l=row&Lm, h=col>>7, d=col&127
//  OUT_MODE 2: AV out, z=bh: Out[((z>>3)*M+row)*1024 + (z&7)*128 + col]
//  OUT_MODE 3: head-T layout [bh][d][l]: addr=((b*8+h)*128+d)<<logL | l
// ---------------------------------------------------------------------------
template<int OUT_MODE, bool RELU, bool BIAS, bool OUT_F32>
__global__ __launch_bounds__(256)
void gemm128(const u16* __restrict__ Aall, const u16* __restrict__ Ball,
             const float* __restrict__ bias, void* __restrict__ OutV,
             int M, int N, int K, int ldOut, int logL,
             long strideA, long strideB)
{
    __shared__ __align__(16) u16 As[128 * 64];
    __shared__ __align__(16) u16 Bs[128 * 64];
    const int z = blockIdx.z;
    const u16* A = Aall + (long)z * strideA;
    const u16* B = Ball + (long)z * strideB;
    const int n0 = blockIdx.x * 128, m0 = blockIdx.y * 128;
    const int tid = threadIdx.x;
    const int w = tid >> 6, lane = tid & 63, q = lane >> 4, li = lane & 15;
    const int wr = w >> 1, wc = w & 1;

    const int srow = tid >> 3;
    const int cg = (tid & 7) ^ (srow & 7);
    const int ldsbase = ((tid >> 6) * 8) * 64;

    f32x4 acc[4][4];
    #pragma unroll
    for (int i = 0; i < 4; i++)
        #pragma unroll
        for (int j = 0; j < 4; j++) acc[i][j] = (f32x4){0.f, 0.f, 0.f, 0.f};

    for (int kt = 0; kt < K; kt += 64) {
        const u16* Ab = A + (long)m0 * K + kt + cg * 8;
        const u16* Bb = B + (long)n0 * K + kt + cg * 8;
        #pragma unroll
        for (int c = 0; c < 4; c++) {
            gload_lds16(Ab + (long)(c * 32 + srow) * K, &As[ldsbase + c * 32 * 64]);
            gload_lds16(Bb + (long)(c * 32 + srow) * K, &Bs[ldsbase + c * 32 * 64]);
        }
        __syncthreads();
        #pragma unroll
        for (int s = 0; s < 2; s++) {
            const int cp = ((s * 4 + q) ^ (li & 7)) * 8;
            bf16x8 av[4], bv[4];
            #pragma unroll
            for (int i = 0; i < 4; i++)
                av[i] = *(bf16x8*)&As[(wr * 64 + i * 16 + li) * 64 + cp];
            #pragma unroll
            for (int j = 0; j < 4; j++)
                bv[j] = *(bf16x8*)&Bs[(wc * 64 + j * 16 + li) * 64 + cp];
            #pragma unroll
            for (int i = 0; i < 4; i++)
                #pragma unroll
                for (int j = 0; j < 4; j++)
                    acc[i][j] = mfma16(av[i], bv[j], acc[i][j]);
        }
        __syncthreads();
    }

    #pragma unroll
    for (int i = 0; i < 4; i++) {
        #pragma unroll
        for (int j = 0; j < 4; j++) {
            const int col = n0 + wc * 64 + j * 16 + li;
            float bvs = 0.f;
            if (BIAS) bvs = bias[col];
            if (OUT_MODE == 3) {
                // rows contiguous in memory: pack 4 r's into one 8B store
                const int row0 = m0 + wr * 64 + i * 16 + q * 4;
                const int Lm = (1 << logL) - 1;
                long base = ((long)(((row0 >> logL) * 8 + (col >> 7)) * 128
                            + (col & 127)) << logL) + (row0 & Lm);
                u16x4 o;
                #pragma unroll
                for (int r = 0; r < 4; r++) {
                    float v = acc[i][j][r] + bvs;
                    if (RELU) v = fmaxf(v, 0.f);
                    o[r] = f2u(v);
                }
                *(u16x4*)((u16*)OutV + base) = o;
            } else {
                #pragma unroll
                for (int r = 0; r < 4; r++) {
                    const int row = m0 + wr * 64 + i * 16 + q * 4 + r;
                    float v = acc[i][j][r] + bvs;
                    if (RELU) v = fmaxf(v, 0.f);
                    long addr;
                    if (OUT_MODE == 0) {
                        addr = (long)row * ldOut + col;
                    } else if (OUT_MODE == 1) {
                        const int Lm = (1 << logL) - 1;
                        addr = ((long)((row >> logL) * 8 + (col >> 7)) << (logL + 7))
                             + ((long)(row & Lm) << 7) + (col & 127);
                    } else {
                        addr = ((long)((z >> 3) * M + row)) * 1024 + ((z & 7) << 7) + col;
                    }
                    if (OUT_F32) ((float*)OutV)[addr] = v;
                    else         ((u16*)OutV)[addr]   = f2u(v);
                }
            }
        }
    }
}

// ---------------------------------------------------------------------------
// 64x64 MFMA GEMM with transposed-operand LDS staging — used for prot AV
// (att^T @ l2). Unchanged from the passing rounds.
// ---------------------------------------------------------------------------
template<bool TRANS_A, bool TRANS_B, int OUT_MODE, bool RELU, bool BIAS, bool OUT_F32>
__global__ __launch_bounds__(256)
void gemm_kernel(const u16* __restrict__ Aall, const u16* __restrict__ Ball,
                 const float* __restrict__ bias, void* __restrict__ OutV,
                 int M, int N, int K, long strideA, long strideB, int logL)
{
    __shared__ __align__(16) u16 As[64][72];
    __shared__ __align__(16) u16 Bs[64][72];
    const int z = blockIdx.z;
    const u16* A  = Aall + (long)z * strideA;
    const u16* Bm = Ball + (long)z * strideB;
    const int n0 = blockIdx.x * 64, m0 = blockIdx.y * 64;
    const int tid = threadIdx.x;
    const int w = tid >> 6, lane = tid & 63, q = lane >> 4, li = lane & 15;
    const int wm = (w >> 1) * 32, wn = (w & 1) * 32;

    f32x4 acc[2][2];
    #pragma unroll
    for (int i = 0; i < 2; i++)
        #pragma unroll
        for (int j = 0; j < 2; j++) acc[i][j] = (f32x4){0.f, 0.f, 0.f, 0.f};

    for (int kt = 0; kt < K; kt += 64) {
        if (!TRANS_A) {
            const int row = tid >> 2, cc = (tid & 3) * 16;
            const u16* src = A + (long)(m0 + row) * K + kt + cc;
            *(u32x4*)&As[row][cc]     = *(const u32x4*)src;
            *(u32x4*)&As[row][cc + 8] = *(const u32x4*)(src + 8);
        } else {
            #pragma unroll
            for (int h = 0; h < 2; h++) {
                const int kr = (tid >> 3) + h * 32, mj = (tid & 7) * 8;
                union { u32x4 v; u16 e[8]; } t;
                t.v = *(const u32x4*)(A + (long)(kt + kr) * M + m0 + mj);
                #pragma unroll
                for (int j = 0; j < 8; j++) As[mj + j][kr] = t.e[j];
            }
        }
        if (!TRANS_B) {
            const int row = tid >> 2, cc = (tid & 3) * 16;
            const u16* src = Bm + (long)(n0 + row) * K + kt + cc;
            *(u32x4*)&Bs[row][cc]     = *(const u32x4*)src;
            *(u32x4*)&Bs[row][cc + 8] = *(const u32x4*)(src + 8);
        } else {
            #pragma unroll
            for (int h = 0; h < 2; h++) {
                const int kr = (tid >> 3) + h * 32, nj = (tid & 7) * 8;
                union { u32x4 v; u16 e[8]; } t;
                t.v = *(const u32x4*)(Bm + (long)(kt + kr) * N + n0 + nj);
                #pragma unroll
                for (int j = 0; j < 8; j++) Bs[nj + j][kr] = t.e[j];
            }
        }
        __syncthreads();
        #pragma unroll
        for (int s = 0; s < 2; s++) {
            bf16x8 a0 = *(bf16x8*)&As[wm + li][s * 32 + q * 8];
            bf16x8 a1 = *(bf16x8*)&As[wm + 16 + li][s * 32 + q * 8];
            bf16x8 b0 = *(bf16x8*)&Bs[wn + li][s * 32 + q * 8];
            bf16x8 b1 = *(bf16x8*)&Bs[wn + 16 + li][s * 32 + q * 8];
            acc[0][0] = mfma16(a0, b0, acc[0][0]);
            acc[0][1] = mfma16(a0, b1, acc[0][1]);
            acc[1][0] = mfma16(a1, b0, acc[1][0]);
            acc[1][1] = mfma16(a1, b1, acc[1][1]);
        }
        __syncthreads();
    }

    #pragma unroll
    for (int i = 0; i < 2; i++) {
        #pragma unroll
        for (int j = 0; j < 2; j++) {
            const int col = n0 + wn + j * 16 + li;
            float bv = 0.f;
            if (BIAS) bv = bias[col];
            #pragma unroll
            for (int r = 0; r < 4; r++) {
                const int row = m0 + wm + i * 16 + q * 4 + r;
                float v = acc[i][j][r] + bv;
                if (RELU) v = fmaxf(v, 0.f);
                long addr;
                if (OUT_MODE == 0) {
                    addr = (long)row * N + col;
                } else if (OUT_MODE == 1) {
                    const int Lm = (1 << logL) - 1;
                    addr = ((long)((row >> logL) * 8 + (col >> 7)) << (logL + 7))
                         + ((long)(row & Lm) << 7) + (col & 127);
                } else {
                    addr = ((long)((z >> 3) * M + row)) * 1024 + ((z & 7) << 7) + col;
                }
                if (OUT_F32) ((float*)OutV)[addr] = v;
                else         ((u16*)OutV)[addr]   = f2u(v);
            }
        }
    }
}

// ---------------------------------------------------------------------------
// Attention v3: grid 512 blocks, id = q*128 + h*16 + b so that all blocks of
// one bh (4 l-quarters) and all heads of one b map to XCD b%8 (id%8==b%8) —
// p1[bh] and inter[b] stay L2-local. Block: 256 threads (4 waves), loops 4
// m-tiles of 16 l-rows; wave w owns p-cols w*256..w*256+255.
// ---------------------------------------------------------------------------
__global__ __launch_bounds__(256, 2)
void attn_kernel(const u16* __restrict__ l1, const u16* __restrict__ p1,
                 const float* __restrict__ inter, u16* __restrict__ att)
{
    __shared__ __align__(16) u16 As[16][136];
    __shared__ float wmax[4][16];
    __shared__ float wsum[4][16];
    const int id = blockIdx.x;
    const int b = id & 15, h = (id >> 4) & 7, q4 = id >> 7;
    const int bh = b * 8 + h;
    const int tid = threadIdx.x;
    const int w = tid >> 6, lane = tid & 63, qq = lane >> 4, li = lane & 15;
    const float rscale = 0.08838834764831845f; // 1/sqrt(128)

    for (int mt = 0; mt < 4; mt++) {
        const int m0 = q4 * 64 + mt * 16;
        __syncthreads();   // protect As/wsum reuse across iterations
        {
            const int row = tid >> 4, col = (tid & 15) * 8;
            *(u32x4*)&As[row][col] =
                *(const u32x4*)(l1 + ((long)bh * 256 + m0 + row) * 128 + col);
        }
        __syncthreads();

        bf16x8 af[4];
        #pragma unroll
        for (int s = 0; s < 4; s++) af[s] = *(bf16x8*)&As[li][s * 32 + qq * 8];

        float sv[16][4];
        #pragma unroll
        for (int t = 0; t < 16; t++) {
            const int n0 = w * 256 + t * 16;
            const u16* bp = p1 + ((long)bh * 1024 + n0 + li) * 128 + qq * 8;
            f32x4 acc = (f32x4){0.f, 0.f, 0.f, 0.f};
            #pragma unroll
            for (int s = 0; s < 4; s++) {
                bf16x8 bfg = *(const bf16x8*)(bp + s * 32);
                acc = mfma16(af[s], bfg, acc);
            }
            const float* ip = inter + ((long)b * 256 + m0 + qq * 4) * 1024 + n0 + li;
            #pragma unroll
            for (int r = 0; r < 4; r++)
                sv[t][r] = acc[r] * rscale * ip[(long)r * 1024];
        }

        #pragma unroll
        for (int r = 0; r < 4; r++) {
            float m = sv[0][r];
            #pragma unroll
            for (int t = 1; t < 16; t++) m = fmaxf(m, sv[t][r]);
            for (int d = 1; d < 16; d <<= 1) m = fmaxf(m, __shfl_xor(m, d, 64));
            if (li == 0) wmax[w][qq * 4 + r] = m;
        }
        __syncthreads();
        float gmax[4];
        #pragma unroll
        for (int r = 0; r < 4; r++)
            gmax[r] = fmaxf(fmaxf(wmax[0][qq * 4 + r], wmax[1][qq * 4 + r]),
                            fmaxf(wmax[2][qq * 4 + r], wmax[3][qq * 4 + r]));
        #pragma unroll
        for (int r = 0; r < 4; r++) {
            float s = 0.f;
            #pragma unroll
            for (int t = 0; t < 16; t++) {
                float e = __expf(sv[t][r] - gmax[r]);
                sv[t][r] = e;
                s += e;
            }
            for (int d = 1; d < 16; d <<= 1) s += __shfl_xor(s, d, 64);
            if (li == 0) wsum[w][qq * 4 + r] = s;
        }
        __syncthreads();
        float inv[4];
        #pragma unroll
        for (int r = 0; r < 4; r++) {
            float s = wsum[0][qq * 4 + r] + wsum[1][qq * 4 + r]
                    + wsum[2][qq * 4 + r] + wsum[3][qq * 4 + r];
            inv[r] = 1.f / s;
        }
        #pragma unroll
        for (int t = 0; t < 16; t++) {
            #pragma unroll
            for (int r = 0; r < 4; r++) {
                att[((long)bh * 256 + m0 + qq * 4 + r) * 1024
                    + w * 256 + t * 16 + li] = f2u(sv[t][r] * inv[r]);
            }
        }
    }
}

// ---------------------------------------------------------------------------
// Fused 8-way transpose + fp32->bf16 convert for weights: dst[C,R] = bf16(src^T)
// ---------------------------------------------------------------------------
struct TPF { const float* src; u16* dst; int R; int C; };
struct TPF8 { TPF t[8]; };

__global__ __launch_bounds__(256)
void cvtw_kernel(TPF8 args)
{
    TPF tp = args.t[blockIdx.z];
    const int c0 = blockIdx.x * 32, r0 = blockIdx.y * 32;
    if (c0 >= tp.C || r0 >= tp.R) return;
    __shared__ u16 tile[32][33];
    const int tx = threadIdx.x & 31, ty = threadIdx.x >> 5;
    #pragma unroll
    for (int i = 0; i < 4; i++)
        tile[ty + i * 8][tx] = f2u(tp.src[(long)(r0 + ty + i * 8) * tp.C + c0 + tx]);
    __syncthreads();
    #pragma unroll
    for (int i = 0; i < 4; i++)
        tp.dst[(long)(c0 + ty + i * 8) * tp.R + r0 + tx] = tile[tx][ty + i * 8];
}

// ---------------------------------------------------------------------------
// fp32 -> bf16 convert; also writes the residual (right) half of the concat
// buffer: dcat[row*256 + 128 + col]. ligand (z=0), prot (z=1).
// ---------------------------------------------------------------------------
__global__ __launch_bounds__(256)
void cvt2_kernel(const float* __restrict__ a, u16* __restrict__ da,
                 u16* __restrict__ ca, int na,
                 const float* __restrict__ b, u16* __restrict__ db,
                 u16* __restrict__ cb, int nb)
{
    const int zz = blockIdx.y;
    const float* s = zz ? b : a;
    u16* d   = zz ? db : da;
    u16* cat = zz ? cb : ca;
    const int n = zz ? nb : na;
    const int i = (blockIdx.x * 256 + threadIdx.x) * 4;
    if (i >= n) return;
    const float4 v = *(const float4*)(s + i);
    u16x4 o;
    o.x = f2u(v.x); o.y = f2u(v.y); o.z = f2u(v.z); o.w = f2u(v.w);
    *(u16x4*)(d + i) = o;
    const int row = i >> 7, col = i & 127;
    *(u16x4*)(cat + (long)row * 256 + 128 + col) = o;
}

// ---------------------------------------------------------------------------
extern "C" void kernel_launch(void* const* d_in, const int* in_sizes, int n_in,
                              void* d_out, int out_size, void* d_ws, size_t ws_size,
                              hipStream_t stream)
{
    (void)in_sizes; (void)n_in; (void)out_size; (void)ws_size;
    const float* ligand = (const float*)d_in[0];
    const float* prot   = (const float*)d_in[1];
    const float* inter  = (const float*)d_in[2];
    const float* Wl1 = (const float*)d_in[3];  const float* bl1 = (const float*)d_in[4];
    const float* Wl2 = (const float*)d_in[5];  const float* bl2 = (const float*)d_in[6];
    const float* Wp1 = (const float*)d_in[7];  const float* bp1 = (const float*)d_in[8];
    const float* Wp2 = (const float*)d_in[9];  const float* bp2 = (const float*)d_in[10];
    const float* W11 = (const float*)d_in[11]; const float* b11 = (const float*)d_in[12];
    const float* W12 = (const float*)d_in[13]; const float* b12 = (const float*)d_in[14];
    const float* W21 = (const float*)d_in[15]; const float* b21 = (const float*)d_in[16];
    const float* W22 = (const float*)d_in[17]; const float* b22 = (const float*)d_in[18];

    float* out0 = (float*)d_out;                    // [16,256,128]
    float* out1 = out0 + (size_t)16 * 256 * 128;    // [16,1024,128]

    u16* ws = (u16*)d_ws;
    size_t off = 0;
    auto alloc = [&](size_t n) { u16* p = ws + off; off += n; return p; };
    u16* ligb  = alloc(524288);    // bf16 ligand [4096,128]
    u16* protb = alloc(2097152);   // bf16 prot  [16384,128]
    u16* l1v   = alloc(4194304);   // [16,8,256,128]
    u16* l2v   = alloc(4194304);   // [16,8,256,128]
    u16* p1v   = alloc(16777216);  // [16,8,1024,128]
    u16* p2t   = alloc(16777216);  // [16,8,128,1024]  (head-transposed)
    u16* attv  = alloc(33554432);  // [16,8,256,1024]
    u16* lig3  = alloc(4194304);   // [16,256,1024]
    u16* prot3 = alloc(16777216);  // [16,1024,1024]
    u16* clig  = alloc(1048576);   // [4096,256] concat
    u16* cprot = alloc(4194304);   // [16384,256] concat
    u16* Wl1t  = alloc(131072);    // [1024,128]
    u16* Wl2t  = alloc(131072);
    u16* Wp1t  = alloc(131072);
    u16* Wp2t  = alloc(131072);
    u16* W11t  = alloc(131072);    // [128,1024]
    u16* W21t  = alloc(131072);
    u16* W12t  = alloc(32768);     // [128,256]
    u16* W22t  = alloc(32768);

    // input conversion + concat residual halves
    cvt2_kernel<<<dim3(2048, 2), 256, 0, stream>>>(
        ligand, ligb, clig, 524288, prot, protb, cprot, 2097152);

    TPF8 tp;
    tp.t[0] = {Wl1, Wl1t, 128, 1024};
    tp.t[1] = {Wl2, Wl2t, 128, 1024};
    tp.t[2] = {Wp1, Wp1t, 128, 1024};
    tp.t[3] = {Wp2, Wp2t, 128, 1024};
    tp.t[4] = {W11, W11t, 1024, 128};
    tp.t[5] = {W21, W21t, 1024, 128};
    tp.t[6] = {W12, W12t, 256, 128};
    tp.t[7] = {W22, W22t, 256, 128};
    cvtw_kernel<<<dim3(32, 32, 8), 256, 0, stream>>>(tp);

    // projections (128-tile). l1/l2/p1 -> head layout; p2 -> head-T layout.
    gemm128<1,true,true,false><<<dim3(8,32),256,0,stream>>>(
        ligb, Wl1t, bl1, l1v, 4096, 1024, 128, 0, 8, 0, 0);
    gemm128<1,true,true,false><<<dim3(8,32),256,0,stream>>>(
        ligb, Wl2t, bl2, l2v, 4096, 1024, 128, 0, 8, 0, 0);
    gemm128<1,true,true,false><<<dim3(8,128),256,0,stream>>>(
        protb, Wp1t, bp1, p1v, 16384, 1024, 128, 0, 10, 0, 0);
    gemm128<3,true,true,false><<<dim3(8,128),256,0,stream>>>(
        protb, Wp2t, bp2, p2t, 16384, 1024, 128, 0, 10, 0, 0);

    // attention scores + softmax (XCD-swizzled, p1-reusing)
    attn_kernel<<<dim3(512),256,0,stream>>>(l1v, p1v, inter, attv);

    // lig branch: att @ p2 -> [B,LL,H*D]  (128-tile, both operands k-minor)
    gemm128<2,false,false,false><<<dim3(1,2,128),256,0,stream>>>(
        attv, p2t, nullptr, lig3, 256, 128, 1024, 0, 0, 262144, 131072);
    // prot branch: att^T @ l2 -> [B,LP,H*D]  (64-tile transposed staging)
    gemm_kernel<true,true,2,false,false,false><<<dim3(2,16,128),256,0,stream>>>(
        attv, l2v, nullptr, prot3, 1024, 128, 256, 262144, 32768, 0);

    // x @ W11 + b11 / x @ W21 + b21 -> left half of concat buffers
    gemm128<0,false,true,false><<<dim3(1,32),256,0,stream>>>(
        lig3, W11t, b11, clig, 4096, 128, 1024, 256, 0, 0, 0);
    gemm128<0,false,true,false><<<dim3(1,128),256,0,stream>>>(
        prot3, W21t, b21, cprot, 16384, 128, 1024, 256, 0, 0, 0);

    // final relu(x @ W12/W22 + b) -> fp32 outputs
    gemm128<0,true,true,true><<<dim3(1,32),256,0,stream>>>(
        clig, W12t, b12, out0, 4096, 128, 256, 128, 0, 0, 0);
    gemm128<0,true,true,true><<<dim3(1,128),256,0,stream>>>(
        cprot, W22t, b22, out1, 16384, 128, 256, 128, 0, 0, 0);
}

// Round 5
// 431.675 us; speedup vs baseline: 1.0252x; 1.0252x over previous
//
#include <hip/hip_runtime.h>
#include <hip/hip_bf16.h>

typedef unsigned short u16;
typedef __attribute__((ext_vector_type(4))) float f32x4;
typedef __attribute__((ext_vector_type(4))) unsigned int u32x4;
typedef __attribute__((ext_vector_type(4))) unsigned short u16x4;
typedef __attribute__((ext_vector_type(8))) __bf16 bf16x8;

__device__ inline float u2f(u16 u) {
    union { unsigned int i; float f; } x; x.i = ((unsigned int)u) << 16; return x.f;
}
__device__ inline u16 f2u(float f) {
    __hip_bfloat16 b = __float2bfloat16(f);
    return *reinterpret_cast<u16*>(&b);
}
__device__ inline f32x4 mfma16(bf16x8 a, bf16x8 b, f32x4 c) {
    return __builtin_amdgcn_mfma_f32_16x16x32_bf16(a, b, c, 0, 0, 0);
}
__device__ inline void gload_lds16(const u16* g, u16* l) {
    __builtin_amdgcn_global_load_lds(
        (const __attribute__((address_space(1))) unsigned int*)g,
        (__attribute__((address_space(3))) unsigned int*)l, 16, 0, 0);
}

// ---------------------------------------------------------------------------
// 128x128 MFMA GEMM, BK=64, global_load_lds staging, XOR chunk swizzle.
// A: [M,K] row-major. B: [N,K] row-major. Batched via blockIdx.z.
//  OUT_MODE 0: Out[row*ldOut + col]
//  OUT_MODE 1: head layout   [bh][l][d]
//  OUT_MODE 3: head-T layout [bh][d][l]
// ---------------------------------------------------------------------------
template<int OUT_MODE, bool RELU, bool BIAS, bool OUT_F32>
__global__ __launch_bounds__(256)
void gemm128(const u16* __restrict__ Aall, const u16* __restrict__ Ball,
             const float* __restrict__ bias, void* __restrict__ OutV,
             int M, int N, int K, int ldOut, int logL,
             long strideA, long strideB)
{
    __shared__ __align__(16) u16 As[128 * 64];
    __shared__ __align__(16) u16 Bs[128 * 64];
    const int z = blockIdx.z;
    const u16* A = Aall + (long)z * strideA;
    const u16* B = Ball + (long)z * strideB;
    const int n0 = blockIdx.x * 128, m0 = blockIdx.y * 128;
    const int tid = threadIdx.x;
    const int w = tid >> 6, lane = tid & 63, q = lane >> 4, li = lane & 15;
    const int wr = w >> 1, wc = w & 1;

    const int srow = tid >> 3;
    const int cg = (tid & 7) ^ (srow & 7);
    const int ldsbase = ((tid >> 6) * 8) * 64;

    f32x4 acc[4][4];
    #pragma unroll
    for (int i = 0; i < 4; i++)
        #pragma unroll
        for (int j = 0; j < 4; j++) acc[i][j] = (f32x4){0.f, 0.f, 0.f, 0.f};

    for (int kt = 0; kt < K; kt += 64) {
        const u16* Ab = A + (long)m0 * K + kt + cg * 8;
        const u16* Bb = B + (long)n0 * K + kt + cg * 8;
        #pragma unroll
        for (int c = 0; c < 4; c++) {
            gload_lds16(Ab + (long)(c * 32 + srow) * K, &As[ldsbase + c * 32 * 64]);
            gload_lds16(Bb + (long)(c * 32 + srow) * K, &Bs[ldsbase + c * 32 * 64]);
        }
        __syncthreads();
        #pragma unroll
        for (int s = 0; s < 2; s++) {
            const int cp = ((s * 4 + q) ^ (li & 7)) * 8;
            bf16x8 av[4], bv[4];
            #pragma unroll
            for (int i = 0; i < 4; i++)
                av[i] = *(bf16x8*)&As[(wr * 64 + i * 16 + li) * 64 + cp];
            #pragma unroll
            for (int j = 0; j < 4; j++)
                bv[j] = *(bf16x8*)&Bs[(wc * 64 + j * 16 + li) * 64 + cp];
            #pragma unroll
            for (int i = 0; i < 4; i++)
                #pragma unroll
                for (int j = 0; j < 4; j++)
                    acc[i][j] = mfma16(av[i], bv[j], acc[i][j]);
        }
        __syncthreads();
    }

    #pragma unroll
    for (int i = 0; i < 4; i++) {
        #pragma unroll
        for (int j = 0; j < 4; j++) {
            const int col = n0 + wc * 64 + j * 16 + li;
            float bvs = 0.f;
            if (BIAS) bvs = bias[col];
            if (OUT_MODE == 3) {
                const int row0 = m0 + wr * 64 + i * 16 + q * 4;
                const int Lm = (1 << logL) - 1;
                long base = ((long)(((row0 >> logL) * 8 + (col >> 7)) * 128
                            + (col & 127)) << logL) + (row0 & Lm);
                u16x4 o;
                #pragma unroll
                for (int r = 0; r < 4; r++) {
                    float v = acc[i][j][r] + bvs;
                    if (RELU) v = fmaxf(v, 0.f);
                    o[r] = f2u(v);
                }
                *(u16x4*)((u16*)OutV + base) = o;
            } else {
                #pragma unroll
                for (int r = 0; r < 4; r++) {
                    const int row = m0 + wr * 64 + i * 16 + q * 4 + r;
                    float v = acc[i][j][r] + bvs;
                    if (RELU) v = fmaxf(v, 0.f);
                    long addr;
                    if (OUT_MODE == 0) {
                        addr = (long)row * ldOut + col;
                    } else {
                        const int Lm = (1 << logL) - 1;
                        addr = ((long)((row >> logL) * 8 + (col >> 7)) << (logL + 7))
                             + ((long)(row & Lm) << 7) + (col & 127);
                    }
                    if (OUT_F32) ((float*)OutV)[addr] = v;
                    else         ((u16*)OutV)[addr]   = f2u(v);
                }
            }
        }
    }
}

// ---------------------------------------------------------------------------
// 64x64 MFMA GEMM, transposed-A staging, vectorized B (k-minor). Used for
// prot AV: C[p,d] = att^T @ l2t^T with A=att[l][p] (TRANS_A), B=l2t[bh][d][l].
// OUT_MODE 2: z=bh: Out[((z>>3)*M+row)*1024 + (z&7)*128 + col]
// ---------------------------------------------------------------------------
template<bool TRANS_A, bool TRANS_B, int OUT_MODE, bool RELU, bool BIAS, bool OUT_F32>
__global__ __launch_bounds__(256)
void gemm_kernel(const u16* __restrict__ Aall, const u16* __restrict__ Ball,
                 const float* __restrict__ bias, void* __restrict__ OutV,
                 int M, int N, int K, long strideA, long strideB, int logL)
{
    __shared__ __align__(16) u16 As[64][72];
    __shared__ __align__(16) u16 Bs[64][72];
    const int z = blockIdx.z;
    const u16* A  = Aall + (long)z * strideA;
    const u16* Bm = Ball + (long)z * strideB;
    const int n0 = blockIdx.x * 64, m0 = blockIdx.y * 64;
    const int tid = threadIdx.x;
    const int w = tid >> 6, lane = tid & 63, q = lane >> 4, li = lane & 15;
    const int wm = (w >> 1) * 32, wn = (w & 1) * 32;

    f32x4 acc[2][2];
    #pragma unroll
    for (int i = 0; i < 2; i++)
        #pragma unroll
        for (int j = 0; j < 2; j++) acc[i][j] = (f32x4){0.f, 0.f, 0.f, 0.f};

    for (int kt = 0; kt < K; kt += 64) {
        if (!TRANS_A) {
            const int row = tid >> 2, cc = (tid & 3) * 16;
            const u16* src = A + (long)(m0 + row) * K + kt + cc;
            *(u32x4*)&As[row][cc]     = *(const u32x4*)src;
            *(u32x4*)&As[row][cc + 8] = *(const u32x4*)(src + 8);
        } else {
            #pragma unroll
            for (int h = 0; h < 2; h++) {
                const int kr = (tid >> 3) + h * 32, mj = (tid & 7) * 8;
                union { u32x4 v; u16 e[8]; } t;
                t.v = *(const u32x4*)(A + (long)(kt + kr) * M + m0 + mj);
                #pragma unroll
                for (int j = 0; j < 8; j++) As[mj + j][kr] = t.e[j];
            }
        }
        if (!TRANS_B) {
            const int row = tid >> 2, cc = (tid & 3) * 16;
            const u16* src = Bm + (long)(n0 + row) * K + kt + cc;
            *(u32x4*)&Bs[row][cc]     = *(const u32x4*)src;
            *(u32x4*)&Bs[row][cc + 8] = *(const u32x4*)(src + 8);
        } else {
            #pragma unroll
            for (int h = 0; h < 2; h++) {
                const int kr = (tid >> 3) + h * 32, nj = (tid & 7) * 8;
                union { u32x4 v; u16 e[8]; } t;
                t.v = *(const u32x4*)(Bm + (long)(kt + kr) * N + n0 + nj);
                #pragma unroll
                for (int j = 0; j < 8; j++) Bs[nj + j][kr] = t.e[j];
            }
        }
        __syncthreads();
        #pragma unroll
        for (int s = 0; s < 2; s++) {
            bf16x8 a0 = *(bf16x8*)&As[wm + li][s * 32 + q * 8];
            bf16x8 a1 = *(bf16x8*)&As[wm + 16 + li][s * 32 + q * 8];
            bf16x8 b0 = *(bf16x8*)&Bs[wn + li][s * 32 + q * 8];
            bf16x8 b1 = *(bf16x8*)&Bs[wn + 16 + li][s * 32 + q * 8];
            acc[0][0] = mfma16(a0, b0, acc[0][0]);
            acc[0][1] = mfma16(a0, b1, acc[0][1]);
            acc[1][0] = mfma16(a1, b0, acc[1][0]);
            acc[1][1] = mfma16(a1, b1, acc[1][1]);
        }
        __syncthreads();
    }

    #pragma unroll
    for (int i = 0; i < 2; i++) {
        #pragma unroll
        for (int j = 0; j < 2; j++) {
            const int col = n0 + wn + j * 16 + li;
            float bv = 0.f;
            if (BIAS) bv = bias[col];
            #pragma unroll
            for (int r = 0; r < 4; r++) {
                const int row = m0 + wm + i * 16 + q * 4 + r;
                float v = acc[i][j][r] + bv;
                if (RELU) v = fmaxf(v, 0.f);
                long addr;
                if (OUT_MODE == 0) {
                    addr = (long)row * N + col;
                } else if (OUT_MODE == 1) {
                    const int Lm = (1 << logL) - 1;
                    addr = ((long)((row >> logL) * 8 + (col >> 7)) << (logL + 7))
                         + ((long)(row & Lm) << 7) + (col & 127);
                } else {
                    addr = ((long)((z >> 3) * M + row)) * 1024 + ((z & 7) << 7) + col;
                }
                if (OUT_F32) ((float*)OutV)[addr] = v;
                else         ((u16*)OutV)[addr]   = f2u(v);
            }
        }
    }
}

// ---------------------------------------------------------------------------
// Fused attention: per (m-tile of 16 l-rows, bh):
//   S = l1 @ p1^T * inter/sqrt(128); att = softmax(S) -> global (bf16)
//   AND lig3[b, l, h*128+d] = att @ p2  (fused AV, att chunk via LDS)
// 256 threads = 4 waves; wave w owns p-cols [w*256, w*256+256).
// ---------------------------------------------------------------------------
__global__ __launch_bounds__(256)
void attn_fused(const u16* __restrict__ l1, const u16* __restrict__ p1,
                const u16* __restrict__ p2t, const u16* __restrict__ interb,
                u16* __restrict__ att, u16* __restrict__ lig3)
{
    __shared__ __align__(16) u16 As[16][136];
    __shared__ __align__(16) u16 svl[4 * 4096];   // per-wave 16x256 att chunk / 16x128 f32 O
    __shared__ float wmax[4][16];
    __shared__ float wsum[4][16];
    const int m0 = blockIdx.x * 16;
    const int bh = blockIdx.y;
    const int b = bh >> 3, h = bh & 7;
    const int tid = threadIdx.x;
    const int w = tid >> 6, lane = tid & 63, q = lane >> 4, li = lane & 15;
    const float rscale = 0.08838834764831845f; // 1/sqrt(128)

    // ---- phase 1: QK^T * inter ----
    {
        const int row = tid >> 4, col = (tid & 15) * 8;
        *(u32x4*)&As[row][col] =
            *(const u32x4*)(l1 + ((long)bh * 256 + m0 + row) * 128 + col);
    }
    __syncthreads();

    bf16x8 af[4];
    #pragma unroll
    for (int s = 0; s < 4; s++) af[s] = *(bf16x8*)&As[li][s * 32 + q * 8];

    float sv[16][4];
    #pragma unroll
    for (int t = 0; t < 16; t++) {
        const int n0 = w * 256 + t * 16;
        const u16* bp = p1 + ((long)bh * 1024 + n0 + li) * 128 + q * 8;
        f32x4 acc = (f32x4){0.f, 0.f, 0.f, 0.f};
        #pragma unroll
        for (int s = 0; s < 4; s++) {
            bf16x8 bfg = *(const bf16x8*)(bp + s * 32);
            acc = mfma16(af[s], bfg, acc);
        }
        const u16* ip = interb + ((long)b * 256 + m0 + q * 4) * 1024 + n0 + li;
        #pragma unroll
        for (int r = 0; r < 4; r++)
            sv[t][r] = acc[r] * rscale * u2f(ip[(long)r * 1024]);
    }

    // ---- phase 2: softmax ----
    #pragma unroll
    for (int r = 0; r < 4; r++) {
        float m = sv[0][r];
        #pragma unroll
        for (int t = 1; t < 16; t++) m = fmaxf(m, sv[t][r]);
        for (int d = 1; d < 16; d <<= 1) m = fmaxf(m, __shfl_xor(m, d, 64));
        if (li == 0) wmax[w][q * 4 + r] = m;
    }
    __syncthreads();
    float gmax[4];
    #pragma unroll
    for (int r = 0; r < 4; r++)
        gmax[r] = fmaxf(fmaxf(wmax[0][q * 4 + r], wmax[1][q * 4 + r]),
                        fmaxf(wmax[2][q * 4 + r], wmax[3][q * 4 + r]));
    #pragma unroll
    for (int r = 0; r < 4; r++) {
        float s = 0.f;
        #pragma unroll
        for (int t = 0; t < 16; t++) {
            float e = __expf(sv[t][r] - gmax[r]);
            sv[t][r] = e;
            s += e;
        }
        for (int d = 1; d < 16; d <<= 1) s += __shfl_xor(s, d, 64);
        if (li == 0) wsum[w][q * 4 + r] = s;
    }
    __syncthreads();
    float inv[4];
    #pragma unroll
    for (int r = 0; r < 4; r++) {
        float s = wsum[0][q * 4 + r] + wsum[1][q * 4 + r]
                + wsum[2][q * 4 + r] + wsum[3][q * 4 + r];
        inv[r] = 1.f / s;
    }

    // ---- phase 3: write att (global) + stash bf16 chunk in LDS (XOR-swizzled)
    u16* myl = svl + w * 4096;    // wave-private 16 rows x 256 cols
    #pragma unroll
    for (int t = 0; t < 16; t++) {
        #pragma unroll
        for (int r = 0; r < 4; r++) {
            const float v = sv[t][r] * inv[r];
            const u16 u = f2u(v);
            att[((long)bh * 256 + m0 + q * 4 + r) * 1024
                + w * 256 + t * 16 + li] = u;
            const int row = q * 4 + r;
            const int chunk = (t * 2 + (li >> 3)) ^ (row & 7);
            myl[row * 256 + chunk * 8 + (li & 7)] = u;
        }
    }
    // wave-private LDS: DS ops execute in order per wave, no barrier needed.

    // ---- phase 4: fused AV over this wave's p-range ----
    f32x4 accD[8];
    #pragma unroll
    for (int j = 0; j < 8; j++) accD[j] = (f32x4){0.f, 0.f, 0.f, 0.f};
    #pragma unroll
    for (int kc = 0; kc < 8; kc++) {
        const int ch = (kc * 4 + q) ^ (li & 7);
        bf16x8 afr = *(bf16x8*)&myl[li * 256 + ch * 8];
        const u16* pb = p2t + ((long)bh * 128 + li) * 1024 + w * 256 + kc * 32 + q * 8;
        #pragma unroll
        for (int j = 0; j < 8; j++) {
            bf16x8 bfr = *(const bf16x8*)(pb + (long)j * 16 * 1024);
            accD[j] = mfma16(afr, bfr, accD[j]);
        }
    }

    // ---- phase 5: cross-wave O reduction, write lig3 ----
    float* Ored = (float*)svl + w * 2048;   // 16 x 128 f32, reuses own region
    #pragma unroll
    for (int j = 0; j < 8; j++) {
        #pragma unroll
        for (int r = 0; r < 4; r++)
            Ored[(q * 4 + r) * 128 + j * 16 + li] = accD[j][r];
    }
    __syncthreads();
    {
        const float* base = (const float*)svl;
        const int idx = tid * 8;
        f32x4 s0 = *(const f32x4*)&base[idx];
        f32x4 s1 = *(const f32x4*)&base[idx + 4];
        #pragma unroll
        for (int ww = 1; ww < 4; ww++) {
            s0 += *(const f32x4*)&base[ww * 2048 + idx];
            s1 += *(const f32x4*)&base[ww * 2048 + idx + 4];
        }
        const int row = idx >> 7, col = idx & 127;
        union { u16x4 v[2]; u32x4 q; } o;
        #pragma unroll
        for (int e = 0; e < 4; e++) { o.v[0][e] = f2u(s0[e]); o.v[1][e] = f2u(s1[e]); }
        *(u32x4*)&lig3[((long)b * 256 + m0 + row) * 1024 + h * 128 + col] = o.q;
    }
}

// ---------------------------------------------------------------------------
// Fused 8-way transpose + fp32->bf16 convert for weights: dst[C,R] = bf16(src^T)
// ---------------------------------------------------------------------------
struct TPF { const float* src; u16* dst; int R; int C; };
struct TPF8 { TPF t[8]; };

__global__ __launch_bounds__(256)
void cvtw_kernel(TPF8 args)
{
    TPF tp = args.t[blockIdx.z];
    const int c0 = blockIdx.x * 32, r0 = blockIdx.y * 32;
    if (c0 >= tp.C || r0 >= tp.R) return;
    __shared__ u16 tile[32][33];
    const int tx = threadIdx.x & 31, ty = threadIdx.x >> 5;
    #pragma unroll
    for (int i = 0; i < 4; i++)
        tile[ty + i * 8][tx] = f2u(tp.src[(long)(r0 + ty + i * 8) * tp.C + c0 + tx]);
    __syncthreads();
    #pragma unroll
    for (int i = 0; i < 4; i++)
        tp.dst[(long)(c0 + ty + i * 8) * tp.R + r0 + tx] = tile[tx][ty + i * 8];
}

// ---------------------------------------------------------------------------
// fp32 -> bf16 converts: z=0 ligand (+concat right half), z=1 prot (+concat),
// z=2 inter (plain).
// ---------------------------------------------------------------------------
__global__ __launch_bounds__(256)
void cvt3_kernel(const float* __restrict__ a, u16* __restrict__ da,
                 u16* __restrict__ ca, int na,
                 const float* __restrict__ b, u16* __restrict__ db,
                 u16* __restrict__ cb, int nb,
                 const float* __restrict__ c, u16* __restrict__ dc, int nc)
{
    const int zz = blockIdx.y;
    const float* s = zz == 0 ? a : (zz == 1 ? b : c);
    u16* d   = zz == 0 ? da : (zz == 1 ? db : dc);
    u16* cat = zz == 0 ? ca : (zz == 1 ? cb : nullptr);
    const int n = zz == 0 ? na : (zz == 1 ? nb : nc);
    const int i = (blockIdx.x * 256 + threadIdx.x) * 4;
    if (i >= n) return;
    const float4 v = *(const float4*)(s + i);
    u16x4 o;
    o.x = f2u(v.x); o.y = f2u(v.y); o.z = f2u(v.z); o.w = f2u(v.w);
    *(u16x4*)(d + i) = o;
    if (cat) {
        const int row = i >> 7, col = i & 127;
        *(u16x4*)(cat + (long)row * 256 + 128 + col) = o;
    }
}

// ---------------------------------------------------------------------------
extern "C" void kernel_launch(void* const* d_in, const int* in_sizes, int n_in,
                              void* d_out, int out_size, void* d_ws, size_t ws_size,
                              hipStream_t stream)
{
    (void)in_sizes; (void)n_in; (void)out_size; (void)ws_size;
    const float* ligand = (const float*)d_in[0];
    const float* prot   = (const float*)d_in[1];
    const float* inter  = (const float*)d_in[2];
    const float* Wl1 = (const float*)d_in[3];  const float* bl1 = (const float*)d_in[4];
    const float* Wl2 = (const float*)d_in[5];  const float* bl2 = (const float*)d_in[6];
    const float* Wp1 = (const float*)d_in[7];  const float* bp1 = (const float*)d_in[8];
    const float* Wp2 = (const float*)d_in[9];  const float* bp2 = (const float*)d_in[10];
    const float* W11 = (const float*)d_in[11]; const float* b11 = (const float*)d_in[12];
    const float* W12 = (const float*)d_in[13]; const float* b12 = (const float*)d_in[14];
    const float* W21 = (const float*)d_in[15]; const float* b21 = (const float*)d_in[16];
    const float* W22 = (const float*)d_in[17]; const float* b22 = (const float*)d_in[18];

    float* out0 = (float*)d_out;                    // [16,256,128]
    float* out1 = out0 + (size_t)16 * 256 * 128;    // [16,1024,128]

    u16* ws = (u16*)d_ws;
    size_t off = 0;
    auto alloc = [&](size_t n) { u16* p = ws + off; off += n; return p; };
    u16* ligb  = alloc(524288);    // bf16 ligand [4096,128]
    u16* protb = alloc(2097152);   // bf16 prot  [16384,128]
    u16* intb  = alloc(4194304);   // bf16 inter [16,256,1024]
    u16* l1v   = alloc(4194304);   // [16,8,256,128]
    u16* l2t   = alloc(4194304);   // [16,8,128,256]  (head-T)
    u16* p1v   = alloc(16777216);  // [16,8,1024,128]
    u16* p2t   = alloc(16777216);  // [16,8,128,1024] (head-T)
    u16* attv  = alloc(33554432);  // [16,8,256,1024]
    u16* lig3  = alloc(4194304);   // [16,256,1024]
    u16* prot3 = alloc(16777216);  // [16,1024,1024]
    u16* clig  = alloc(1048576);   // [4096,256] concat
    u16* cprot = alloc(4194304);   // [16384,256] concat
    u16* Wl1t  = alloc(131072);    // [1024,128]
    u16* Wl2t  = alloc(131072);
    u16* Wp1t  = alloc(131072);
    u16* Wp2t  = alloc(131072);
    u16* W11t  = alloc(131072);    // [128,1024]
    u16* W21t  = alloc(131072);
    u16* W12t  = alloc(32768);     // [128,256]
    u16* W22t  = alloc(32768);

    // input conversion + concat residual halves + inter->bf16
    cvt3_kernel<<<dim3(4096, 3), 256, 0, stream>>>(
        ligand, ligb, clig, 524288,
        prot, protb, cprot, 2097152,
        inter, intb, 4194304);

    TPF8 tp;
    tp.t[0] = {Wl1, Wl1t, 128, 1024};
    tp.t[1] = {Wl2, Wl2t, 128, 1024};
    tp.t[2] = {Wp1, Wp1t, 128, 1024};
    tp.t[3] = {Wp2, Wp2t, 128, 1024};
    tp.t[4] = {W11, W11t, 1024, 128};
    tp.t[5] = {W21, W21t, 1024, 128};
    tp.t[6] = {W12, W12t, 256, 128};
    tp.t[7] = {W22, W22t, 256, 128};
    cvtw_kernel<<<dim3(32, 32, 8), 256, 0, stream>>>(tp);

    // projections (128-tile). l1/p1 -> head layout; l2/p2 -> head-T layout.
    gemm128<1,true,true,false><<<dim3(8,32),256,0,stream>>>(
        ligb, Wl1t, bl1, l1v, 4096, 1024, 128, 0, 8, 0, 0);
    gemm128<3,true,true,false><<<dim3(8,32),256,0,stream>>>(
        ligb, Wl2t, bl2, l2t, 4096, 1024, 128, 0, 8, 0, 0);
    gemm128<1,true,true,false><<<dim3(8,128),256,0,stream>>>(
        protb, Wp1t, bp1, p1v, 16384, 1024, 128, 0, 10, 0, 0);
    gemm128<3,true,true,false><<<dim3(8,128),256,0,stream>>>(
        protb, Wp2t, bp2, p2t, 16384, 1024, 128, 0, 10, 0, 0);

    // attention + softmax + fused ligand AV (writes attv and lig3)
    attn_fused<<<dim3(16,128),256,0,stream>>>(l1v, p1v, p2t, intb, attv, lig3);

    // prot branch: att^T @ l2 -> [B,LP,H*D]  (A transposed-staged, B vector)
    gemm_kernel<true,false,2,false,false,false><<<dim3(2,16,128),256,0,stream>>>(
        attv, l2t, nullptr, prot3, 1024, 128, 256, 262144, 32768, 0);

    // x @ W11 + b11 / x @ W21 + b21 -> left half of concat buffers
    gemm128<0,false,true,false><<<dim3(1,32),256,0,stream>>>(
        lig3, W11t, b11, clig, 4096, 128, 1024, 256, 0, 0, 0);
    gemm128<0,false,true,false><<<dim3(1,128),256,0,stream>>>(
        prot3, W21t, b21, cprot, 16384, 128, 1024, 256, 0, 0, 0);

    // final relu(x @ W12/W22 + b) -> fp32 outputs
    gemm128<0,true,true,true><<<dim3(1,32),256,0,stream>>>(
        clig, W12t, b12, out0, 4096, 128, 256, 128, 0, 0, 0);
    gemm128<0,true,true,true><<<dim3(1,128),256,0,stream>>>(
        cprot, W22t, b22, out1, 16384, 128, 256, 128, 0, 0, 0);
}

// Round 7
// 395.283 us; speedup vs baseline: 1.1196x; 1.0921x over previous
//
#include <hip/hip_runtime.h>
#include <hip/hip_bf16.h>

typedef unsigned short u16;
typedef __attribute__((ext_vector_type(4))) float f32x4;
typedef __attribute__((ext_vector_type(4))) unsigned int u32x4;
typedef __attribute__((ext_vector_type(4))) unsigned short u16x4;
typedef __attribute__((ext_vector_type(8))) __bf16 bf16x8;

__device__ inline float u2f(u16 u) {
    union { unsigned int i; float f; } x; x.i = ((unsigned int)u) << 16; return x.f;
}
__device__ inline u16 f2u(float f) {
    __hip_bfloat16 b = __float2bfloat16(f);
    return *reinterpret_cast<u16*>(&b);
}
__device__ inline f32x4 mfma16(bf16x8 a, bf16x8 b, f32x4 c) {
    return __builtin_amdgcn_mfma_f32_16x16x32_bf16(a, b, c, 0, 0, 0);
}
__device__ inline void gload_lds16(const u16* g, u16* l) {
    __builtin_amdgcn_global_load_lds(
        (const __attribute__((address_space(1))) unsigned int*)g,
        (__attribute__((address_space(3))) unsigned int*)l, 16, 0, 0);
}

// ---------------------------------------------------------------------------
// 128x128 MFMA GEMM, BK=64, global_load_lds staging, XOR chunk swizzle.
// A: [M,K] k-minor. B: [N,K] k-minor. Batched via blockIdx.z (strideA/B).
//  STACK: A is [A (ld 1024, k<1024) | A2 (ld 128, k>=1024)] (K=1152 case)
//  OUT_MODE 0: Out[row*ldOut + col]
//  OUT_MODE 1: head layout   [bh][l][d]
//  OUT_MODE 2: z=bh batched: Out[((z>>3)*M+row)*1024 + (z&7)*128 + col]
//  OUT_MODE 3: head-T layout [bh][d][l]
// ---------------------------------------------------------------------------
template<int OUT_MODE, bool RELU, bool BIAS, bool OUT_F32, bool STACK>
__global__ __launch_bounds__(256)
void gemm128(const u16* __restrict__ Aall, const u16* __restrict__ A2,
             const u16* __restrict__ Ball,
             const float* __restrict__ bias, void* __restrict__ OutV,
             int M, int N, int K, int ldOut, int logL,
             long strideA, long strideB)
{
    __shared__ __align__(16) u16 As[128 * 64];
    __shared__ __align__(16) u16 Bs[128 * 64];
    const int z = blockIdx.z;
    const u16* A = Aall + (long)z * strideA;
    const u16* B = Ball + (long)z * strideB;
    const int n0 = blockIdx.x * 128, m0 = blockIdx.y * 128;
    const int tid = threadIdx.x;
    const int w = tid >> 6, lane = tid & 63, q = lane >> 4, li = lane & 15;
    const int wr = w >> 1, wc = w & 1;

    const int srow = tid >> 3;
    const int cg = (tid & 7) ^ (srow & 7);
    const int ldsbase = ((tid >> 6) * 8) * 64;

    f32x4 acc[4][4];
    #pragma unroll
    for (int i = 0; i < 4; i++)
        #pragma unroll
        for (int j = 0; j < 4; j++) acc[i][j] = (f32x4){0.f, 0.f, 0.f, 0.f};

    for (int kt = 0; kt < K; kt += 64) {
        const u16* Abase;
        long lda;
        int ktA;
        if (STACK && kt >= 1024) { Abase = A2; lda = 128; ktA = kt - 1024; }
        else { Abase = A; lda = STACK ? 1024 : K; ktA = kt; }
        const u16* Ab = Abase + (long)m0 * lda + ktA + cg * 8;
        const u16* Bb = B + (long)n0 * K + kt + cg * 8;
        #pragma unroll
        for (int c = 0; c < 4; c++) {
            gload_lds16(Ab + (long)(c * 32 + srow) * lda, &As[ldsbase + c * 32 * 64]);
            gload_lds16(Bb + (long)(c * 32 + srow) * K,   &Bs[ldsbase + c * 32 * 64]);
        }
        __syncthreads();
        #pragma unroll
        for (int s = 0; s < 2; s++) {
            const int cp = ((s * 4 + q) ^ (li & 7)) * 8;
            bf16x8 av[4], bv[4];
            #pragma unroll
            for (int i = 0; i < 4; i++)
                av[i] = *(bf16x8*)&As[(wr * 64 + i * 16 + li) * 64 + cp];
            #pragma unroll
            for (int j = 0; j < 4; j++)
                bv[j] = *(bf16x8*)&Bs[(wc * 64 + j * 16 + li) * 64 + cp];
            #pragma unroll
            for (int i = 0; i < 4; i++)
                #pragma unroll
                for (int j = 0; j < 4; j++)
                    acc[i][j] = mfma16(av[i], bv[j], acc[i][j]);
        }
        __syncthreads();
    }

    #pragma unroll
    for (int i = 0; i < 4; i++) {
        #pragma unroll
        for (int j = 0; j < 4; j++) {
            const int col = n0 + wc * 64 + j * 16 + li;
            float bvs = 0.f;
            if (BIAS) bvs = bias[col];
            if (OUT_MODE == 3) {
                const int row0 = m0 + wr * 64 + i * 16 + q * 4;
                const int Lm = (1 << logL) - 1;
                long base = ((long)(((row0 >> logL) * 8 + (col >> 7)) * 128
                            + (col & 127)) << logL) + (row0 & Lm);
                u16x4 o;
                #pragma unroll
                for (int r = 0; r < 4; r++) {
                    float v = acc[i][j][r] + bvs;
                    if (RELU) v = fmaxf(v, 0.f);
                    o[r] = f2u(v);
                }
                *(u16x4*)((u16*)OutV + base) = o;
            } else {
                #pragma unroll
                for (int r = 0; r < 4; r++) {
                    const int row = m0 + wr * 64 + i * 16 + q * 4 + r;
                    float v = acc[i][j][r] + bvs;
                    if (RELU) v = fmaxf(v, 0.f);
                    long addr;
                    if (OUT_MODE == 0) {
                        addr = (long)row * ldOut + col;
                    } else if (OUT_MODE == 1) {
                        const int Lm = (1 << logL) - 1;
                        addr = ((long)((row >> logL) * 8 + (col >> 7)) << (logL + 7))
                             + ((long)(row & Lm) << 7) + (col & 127);
                    } else {
                        addr = ((long)((z >> 3) * M + row)) * 1024 + ((z & 7) << 7) + col;
                    }
                    if (OUT_F32) ((float*)OutV)[addr] = v;
                    else         ((u16*)OutV)[addr]   = f2u(v);
                }
            }
        }
    }
}

// ---------------------------------------------------------------------------
// 64x64 MFMA GEMM, used for prot AV: C[p,d] = att^T @ l2 with
// A = att[l][p] (TRANS_A scalar staging), B = l2t[bh][d][l] (k-minor vector).
// OUT_MODE 2: z=bh: Out[((z>>3)*M+row)*1024 + (z&7)*128 + col]
// ---------------------------------------------------------------------------
template<bool TRANS_A, int OUT_MODE, bool RELU, bool BIAS, bool OUT_F32>
__global__ __launch_bounds__(256)
void gemm_kernel(const u16* __restrict__ Aall, const u16* __restrict__ Ball,
                 const float* __restrict__ bias, void* __restrict__ OutV,
                 int M, int N, int K, long strideA, long strideB, int logL)
{
    __shared__ __align__(16) u16 As[64][72];
    __shared__ __align__(16) u16 Bs[64][72];
    const int z = blockIdx.z;
    const u16* A  = Aall + (long)z * strideA;
    const u16* Bm = Ball + (long)z * strideB;
    const int n0 = blockIdx.x * 64, m0 = blockIdx.y * 64;
    const int tid = threadIdx.x;
    const int w = tid >> 6, lane = tid & 63, q = lane >> 4, li = lane & 15;
    const int wm = (w >> 1) * 32, wn = (w & 1) * 32;

    f32x4 acc[2][2];
    #pragma unroll
    for (int i = 0; i < 2; i++)
        #pragma unroll
        for (int j = 0; j < 2; j++) acc[i][j] = (f32x4){0.f, 0.f, 0.f, 0.f};

    for (int kt = 0; kt < K; kt += 64) {
        if (!TRANS_A) {
            const int row = tid >> 2, cc = (tid & 3) * 16;
            const u16* src = A + (long)(m0 + row) * K + kt + cc;
            *(u32x4*)&As[row][cc]     = *(const u32x4*)src;
            *(u32x4*)&As[row][cc + 8] = *(const u32x4*)(src + 8);
        } else {
            #pragma unroll
            for (int h = 0; h < 2; h++) {
                const int kr = (tid >> 3) + h * 32, mj = (tid & 7) * 8;
                union { u32x4 v; u16 e[8]; } t;
                t.v = *(const u32x4*)(A + (long)(kt + kr) * M + m0 + mj);
                #pragma unroll
                for (int j = 0; j < 8; j++) As[mj + j][kr] = t.e[j];
            }
        }
        {
            const int row = tid >> 2, cc = (tid & 3) * 16;
            const u16* src = Bm + (long)(n0 + row) * K + kt + cc;
            *(u32x4*)&Bs[row][cc]     = *(const u32x4*)src;
            *(u32x4*)&Bs[row][cc + 8] = *(const u32x4*)(src + 8);
        }
        __syncthreads();
        #pragma unroll
        for (int s = 0; s < 2; s++) {
            bf16x8 a0 = *(bf16x8*)&As[wm + li][s * 32 + q * 8];
            bf16x8 a1 = *(bf16x8*)&As[wm + 16 + li][s * 32 + q * 8];
            bf16x8 b0 = *(bf16x8*)&Bs[wn + li][s * 32 + q * 8];
            bf16x8 b1 = *(bf16x8*)&Bs[wn + 16 + li][s * 32 + q * 8];
            acc[0][0] = mfma16(a0, b0, acc[0][0]);
            acc[0][1] = mfma16(a0, b1, acc[0][1]);
            acc[1][0] = mfma16(a1, b0, acc[1][0]);
            acc[1][1] = mfma16(a1, b1, acc[1][1]);
        }
        __syncthreads();
    }

    #pragma unroll
    for (int i = 0; i < 2; i++) {
        #pragma unroll
        for (int j = 0; j < 2; j++) {
            const int col = n0 + wn + j * 16 + li;
            float bv = 0.f;
            if (BIAS) bv = bias[col];
            #pragma unroll
            for (int r = 0; r < 4; r++) {
                const int row = m0 + wm + i * 16 + q * 4 + r;
                float v = acc[i][j][r] + bv;
                if (RELU) v = fmaxf(v, 0.f);
                long addr;
                if (OUT_MODE == 0) {
                    addr = (long)row * N + col;
                } else {
                    addr = ((long)((z >> 3) * M + row)) * 1024 + ((z & 7) << 7) + col;
                }
                if (OUT_F32) ((float*)OutV)[addr] = v;
                else         ((u16*)OutV)[addr]   = f2u(v);
            }
        }
    }
}

// ---------------------------------------------------------------------------
// Attention v1 (proven 95.5us shape) with bf16 inter: per (m-tile 16, bh):
// S = l1 @ p1^T * inter/sqrt(128), softmax over LP=1024, write att bf16.
// 4 waves; wave w owns p-cols [w*256, w*256+256).
// ---------------------------------------------------------------------------
__global__ __launch_bounds__(256)
void attn_kernel(const u16* __restrict__ l1, const u16* __restrict__ p1,
                 const u16* __restrict__ interb, u16* __restrict__ att)
{
    __shared__ __align__(16) u16 As[16][136];
    __shared__ float wmax[4][16];
    __shared__ float wsum[4][16];
    const int bh = blockIdx.y;
    const int b  = bh >> 3;
    const int m0 = blockIdx.x * 16;
    const int tid = threadIdx.x;
    const int w = tid >> 6, lane = tid & 63, q = lane >> 4, li = lane & 15;

    {
        const int row = tid >> 4, col = (tid & 15) * 8;
        *(u32x4*)&As[row][col] =
            *(const u32x4*)(l1 + ((long)bh * 256 + m0 + row) * 128 + col);
    }
    __syncthreads();

    bf16x8 af[4];
    #pragma unroll
    for (int s = 0; s < 4; s++) af[s] = *(bf16x8*)&As[li][s * 32 + q * 8];

    float sv[16][4];
    const float rscale = 0.08838834764831845f; // 1/sqrt(128)
    for (int t = 0; t < 16; t++) {
        const int n0 = w * 256 + t * 16;
        const u16* bp = p1 + ((long)bh * 1024 + n0 + li) * 128 + q * 8;
        f32x4 acc = (f32x4){0.f, 0.f, 0.f, 0.f};
        #pragma unroll
        for (int s = 0; s < 4; s++) {
            bf16x8 bfg = *(const bf16x8*)(bp + s * 32);
            acc = mfma16(af[s], bfg, acc);
        }
        const int pcol = n0 + li;
        #pragma unroll
        for (int r = 0; r < 4; r++) {
            const int l = m0 + q * 4 + r;
            float iv = u2f(interb[((long)b * 256 + l) * 1024 + pcol]);
            sv[t][r] = acc[r] * rscale * iv;
        }
    }

    float rmax[4];
    #pragma unroll
    for (int r = 0; r < 4; r++) {
        float m = sv[0][r];
        #pragma unroll
        for (int t = 1; t < 16; t++) m = fmaxf(m, sv[t][r]);
        for (int d = 1; d < 16; d <<= 1) m = fmaxf(m, __shfl_xor(m, d, 64));
        rmax[r] = m;
    }
    if (li == 0) {
        #pragma unroll
        for (int r = 0; r < 4; r++) wmax[w][q * 4 + r] = rmax[r];
    }
    __syncthreads();
    float gmax[4];
    #pragma unroll
    for (int r = 0; r < 4; r++) {
        gmax[r] = fmaxf(fmaxf(wmax[0][q * 4 + r], wmax[1][q * 4 + r]),
                        fmaxf(wmax[2][q * 4 + r], wmax[3][q * 4 + r]));
    }
    #pragma unroll
    for (int r = 0; r < 4; r++) {
        float s = 0.f;
        #pragma unroll
        for (int t = 0; t < 16; t++) {
            float e = __expf(sv[t][r] - gmax[r]);
            sv[t][r] = e;
            s += e;
        }
        for (int d = 1; d < 16; d <<= 1) s += __shfl_xor(s, d, 64);
        if (li == 0) wsum[w][q * 4 + r] = s;
    }
    __syncthreads();
    float inv[4];
    #pragma unroll
    for (int r = 0; r < 4; r++) {
        float s = wsum[0][q * 4 + r] + wsum[1][q * 4 + r]
                + wsum[2][q * 4 + r] + wsum[3][q * 4 + r];
        inv[r] = 1.f / s;
    }
    for (int t = 0; t < 16; t++) {
        #pragma unroll
        for (int r = 0; r < 4; r++) {
            const int l = m0 + q * 4 + r;
            const int pcol = w * 256 + t * 16 + li;
            att[((long)bh * 256 + l) * 1024 + pcol] = f2u(sv[t][r] * inv[r]);
        }
    }
}

// ---------------------------------------------------------------------------
// Fused 8-way transpose + fp32->bf16 convert for weights: dst[C,R] = bf16(src^T)
// ---------------------------------------------------------------------------
struct TPF { const float* src; u16* dst; int R; int C; };
struct TPF8 { TPF t[8]; };

__global__ __launch_bounds__(256)
void cvtw_kernel(TPF8 args)
{
    TPF tp = args.t[blockIdx.z];
    const int c0 = blockIdx.x * 32, r0 = blockIdx.y * 32;
    if (c0 >= tp.C || r0 >= tp.R) return;
    __shared__ u16 tile[32][33];
    const int tx = threadIdx.x & 31, ty = threadIdx.x >> 5;
    #pragma unroll
    for (int i = 0; i < 4; i++)
        tile[ty + i * 8][tx] = f2u(tp.src[(long)(r0 + ty + i * 8) * tp.C + c0 + tx]);
    __syncthreads();
    #pragma unroll
    for (int i = 0; i < 4; i++)
        tp.dst[(long)(c0 + ty + i * 8) * tp.R + r0 + tx] = tile[tx][ty + i * 8];
}

// ---------------------------------------------------------------------------
// Weight-combine: Wst[n][0:1024] = (Wmid^T stored [128][1024]) combined with
// Wout^T [128][256]: Wst[n][k] = sum_j Wout_t[n][j] * Wmid_t[j][k];
// Wst[n][1024+c] = Wout_t[n][128+c]; bc[n] = bout[n] + sum_j bmid[j]*Wout_t[n][j]
// blockIdx.y: 0 = lig (W11/W12), 1 = prot (W21/W22). blockIdx.x = n.
// ---------------------------------------------------------------------------
__global__ __launch_bounds__(256)
void wcomb_kernel(const u16* __restrict__ Wm0, const u16* __restrict__ Wo0,
                  const float* __restrict__ bm0, const float* __restrict__ bo0,
                  u16* __restrict__ Wst0, float* __restrict__ bc0,
                  const u16* __restrict__ Wm1, const u16* __restrict__ Wo1,
                  const float* __restrict__ bm1, const float* __restrict__ bo1,
                  u16* __restrict__ Wst1, float* __restrict__ bc1)
{
    const int zz = blockIdx.y;
    const u16* Wm = zz ? Wm1 : Wm0;
    const u16* Wo = zz ? Wo1 : Wo0;
    const float* bmid = zz ? bm1 : bm0;
    const float* bout = zz ? bo1 : bo0;
    u16* Wst = zz ? Wst1 : Wst0;
    float* bc = zz ? bc1 : bc0;
    const int n = blockIdx.x;
    const int tid = threadIdx.x;
    __shared__ float wrow[128];
    if (tid < 128) wrow[tid] = u2f(Wo[n * 256 + tid]);
    __syncthreads();
    for (int k = tid; k < 1024; k += 256) {
        float acc = 0.f;
        #pragma unroll 4
        for (int j = 0; j < 128; j++) acc += wrow[j] * u2f(Wm[(long)j * 1024 + k]);
        Wst[(long)n * 1152 + k] = f2u(acc);
    }
    if (tid < 128) Wst[(long)n * 1152 + 1024 + tid] = Wo[n * 256 + 128 + tid];
    if (tid == 0) {
        float acc = bout[n];
        for (int j = 0; j < 128; j++) acc += bmid[j] * wrow[j];
        bc[n] = acc;
    }
}

// ---------------------------------------------------------------------------
// fp32 -> bf16 converts: z=0 ligand, z=1 prot, z=2 inter
// ---------------------------------------------------------------------------
__global__ __launch_bounds__(256)
void cvt3_kernel(const float* __restrict__ a, u16* __restrict__ da, int na,
                 const float* __restrict__ b, u16* __restrict__ db, int nb,
                 const float* __restrict__ c, u16* __restrict__ dc, int nc)
{
    const int zz = blockIdx.y;
    const float* s = zz == 0 ? a : (zz == 1 ? b : c);
    u16* d = zz == 0 ? da : (zz == 1 ? db : dc);
    const int n = zz == 0 ? na : (zz == 1 ? nb : nc);
    const int i = (blockIdx.x * 256 + threadIdx.x) * 4;
    if (i >= n) return;
    const float4 v = *(const float4*)(s + i);
    u16x4 o;
    o.x = f2u(v.x); o.y = f2u(v.y); o.z = f2u(v.z); o.w = f2u(v.w);
    *(u16x4*)(d + i) = o;
}

// ---------------------------------------------------------------------------
extern "C" void kernel_launch(void* const* d_in, const int* in_sizes, int n_in,
                              void* d_out, int out_size, void* d_ws, size_t ws_size,
                              hipStream_t stream)
{
    (void)in_sizes; (void)n_in; (void)out_size; (void)ws_size;
    const float* ligand = (const float*)d_in[0];
    const float* prot   = (const float*)d_in[1];
    const float* inter  = (const float*)d_in[2];
    const float* Wl1 = (const float*)d_in[3];  const float* bl1 = (const float*)d_in[4];
    const float* Wl2 = (const float*)d_in[5];  const float* bl2 = (const float*)d_in[6];
    const float* Wp1 = (const float*)d_in[7];  const float* bp1 = (const float*)d_in[8];
    const float* Wp2 = (const float*)d_in[9];  const float* bp2 = (const float*)d_in[10];
    const float* W11 = (const float*)d_in[11]; const float* b11 = (const float*)d_in[12];
    const float* W12 = (const float*)d_in[13]; const float* b12 = (const float*)d_in[14];
    const float* W21 = (const float*)d_in[15]; const float* b21 = (const float*)d_in[16];
    const float* W22 = (const float*)d_in[17]; const float* b22 = (const float*)d_in[18];

    float* out0 = (float*)d_out;                    // [16,256,128]
    float* out1 = out0 + (size_t)16 * 256 * 128;    // [16,1024,128]

    u16* ws = (u16*)d_ws;
    size_t off = 0;
    auto alloc = [&](size_t n) { u16* p = ws + off; off += n; return p; };
    u16* ligb  = alloc(524288);    // bf16 ligand [4096,128]
    u16* protb = alloc(2097152);   // bf16 prot  [16384,128]
    u16* intb  = alloc(4194304);   // bf16 inter [16,256,1024]
    u16* l1v   = alloc(4194304);   // [16,8,256,128]
    u16* l2t   = alloc(4194304);   // [16,8,128,256]  (head-T)
    u16* p1v   = alloc(16777216);  // [16,8,1024,128]
    u16* p2t   = alloc(16777216);  // [16,8,128,1024] (head-T)
    u16* attv  = alloc(33554432);  // [16,8,256,1024]
    u16* lig3  = alloc(4194304);   // [16,256,1024]
    u16* prot3 = alloc(16777216);  // [16,1024,1024]
    u16* Wl1t  = alloc(131072);    // [1024,128]
    u16* Wl2t  = alloc(131072);
    u16* Wp1t  = alloc(131072);
    u16* Wp2t  = alloc(131072);
    u16* W11t  = alloc(131072);    // [128,1024] = W11^T
    u16* W21t  = alloc(131072);    // [128,1024] = W21^T
    u16* W12t  = alloc(32768);     // [128,256]  = W12^T
    u16* W22t  = alloc(32768);     // [128,256]  = W22^T
    u16* WstL  = alloc(147456);    // [128,1152] combined lig weight
    u16* WstP  = alloc(147456);    // [128,1152] combined prot weight
    float* bcL = (float*)alloc(256);  // [128] f32
    float* bcP = (float*)alloc(256);  // [128] f32

    // input conversion (ligand, prot, inter) -> bf16
    cvt3_kernel<<<dim3(4096, 3), 256, 0, stream>>>(
        ligand, ligb, 524288, prot, protb, 2097152, inter, intb, 4194304);

    TPF8 tp;
    tp.t[0] = {Wl1, Wl1t, 128, 1024};
    tp.t[1] = {Wl2, Wl2t, 128, 1024};
    tp.t[2] = {Wp1, Wp1t, 128, 1024};
    tp.t[3] = {Wp2, Wp2t, 128, 1024};
    tp.t[4] = {W11, W11t, 1024, 128};
    tp.t[5] = {W21, W21t, 1024, 128};
    tp.t[6] = {W12, W12t, 256, 128};
    tp.t[7] = {W22, W22t, 256, 128};
    cvtw_kernel<<<dim3(32, 32, 8), 256, 0, stream>>>(tp);

    // combine W11@W12top / W21@W22top + residual halves + biases
    wcomb_kernel<<<dim3(128, 2), 256, 0, stream>>>(
        W11t, W12t, b11, b12, WstL, bcL,
        W21t, W22t, b21, b22, WstP, bcP);

    // projections (128-tile). l1/p1 -> head layout; l2/p2 -> head-T layout.
    gemm128<1,true,true,false,false><<<dim3(8,32),256,0,stream>>>(
        ligb, nullptr, Wl1t, bl1, l1v, 4096, 1024, 128, 0, 8, 0, 0);
    gemm128<3,true,true,false,false><<<dim3(8,32),256,0,stream>>>(
        ligb, nullptr, Wl2t, bl2, l2t, 4096, 1024, 128, 0, 8, 0, 0);
    gemm128<1,true,true,false,false><<<dim3(8,128),256,0,stream>>>(
        protb, nullptr, Wp1t, bp1, p1v, 16384, 1024, 128, 0, 10, 0, 0);
    gemm128<3,true,true,false,false><<<dim3(8,128),256,0,stream>>>(
        protb, nullptr, Wp2t, bp2, p2t, 16384, 1024, 128, 0, 10, 0, 0);

    // attention scores + softmax (proven v1 shape, bf16 inter)
    attn_kernel<<<dim3(16,128),256,0,stream>>>(l1v, p1v, intb, attv);

    // lig branch: att @ p2 -> lig3 [B,LL,H*D] (128-tile, both k-minor)
    gemm128<2,false,false,false,false><<<dim3(1,2,128),256,0,stream>>>(
        attv, nullptr, p2t, nullptr, lig3, 256, 128, 1024, 0, 0, 262144, 131072);
    // prot branch: att^T @ l2 -> prot3 [B,LP,H*D]
    gemm_kernel<true,2,false,false,false><<<dim3(2,16,128),256,0,stream>>>(
        attv, l2t, nullptr, prot3, 1024, 128, 256, 262144, 32768, 0);

    // fused final: out = relu([X, resid] @ Wst^T + bc), K = 1024 + 128
    gemm128<0,true,true,true,true><<<dim3(1,32),256,0,stream>>>(
        lig3, ligb, WstL, bcL, out0, 4096, 128, 1152, 128, 0, 0, 0);
    gemm128<0,true,true,true,true><<<dim3(1,128),256,0,stream>>>(
        prot3, protb, WstP, bcP, out1, 16384, 128, 1152, 128, 0, 0, 0);
}

// Round 8
// 393.713 us; speedup vs baseline: 1.1241x; 1.0040x over previous
//
#include <hip/hip_runtime.h>
#include <hip/hip_bf16.h>

typedef unsigned short u16;
typedef __attribute__((ext_vector_type(4))) float f32x4;
typedef __attribute__((ext_vector_type(4))) unsigned int u32x4;
typedef __attribute__((ext_vector_type(4))) unsigned short u16x4;
typedef __attribute__((ext_vector_type(8))) __bf16 bf16x8;

__device__ inline float u2f(u16 u) {
    union { unsigned int i; float f; } x; x.i = ((unsigned int)u) << 16; return x.f;
}
__device__ inline u16 f2u(float f) {
    __hip_bfloat16 b = __float2bfloat16(f);
    return *reinterpret_cast<u16*>(&b);
}
__device__ inline f32x4 mfma16(bf16x8 a, bf16x8 b, f32x4 c) {
    return __builtin_amdgcn_mfma_f32_16x16x32_bf16(a, b, c, 0, 0, 0);
}
__device__ inline void gload_lds16(const u16* g, u16* l) {
    __builtin_amdgcn_global_load_lds(
        (const __attribute__((address_space(1))) unsigned int*)g,
        (__attribute__((address_space(3))) unsigned int*)l, 16, 0, 0);
}

// ---------------------------------------------------------------------------
// 128x128 MFMA GEMM, BK=64, global_load_lds staging, XOR chunk swizzle.
// A: [M,K] k-minor. B: [N,K] k-minor. Batched via blockIdx.z (strideA/B).
//  STACK: A is [A (ld 1024, k<1024) | A2 (ld 128, k>=1024)] (K=1152 case)
//  OUT_MODE 0: Out[row*ldOut + col]
//  OUT_MODE 1: head layout   [bh][l][d]
//  OUT_MODE 2: z=bh batched: Out[((z>>3)*M+row)*1024 + (z&7)*128 + col]
//  OUT_MODE 3: head-T layout [bh][d][l]
// ---------------------------------------------------------------------------
template<int OUT_MODE, bool RELU, bool BIAS, bool OUT_F32, bool STACK>
__global__ __launch_bounds__(256)
void gemm128(const u16* __restrict__ Aall, const u16* __restrict__ A2,
             const u16* __restrict__ Ball,
             const float* __restrict__ bias, void* __restrict__ OutV,
             int M, int N, int K, int ldOut, int logL,
             long strideA, long strideB)
{
    __shared__ __align__(16) u16 As[128 * 64];
    __shared__ __align__(16) u16 Bs[128 * 64];
    const int z = blockIdx.z;
    const u16* A = Aall + (long)z * strideA;
    const u16* B = Ball + (long)z * strideB;
    const int n0 = blockIdx.x * 128, m0 = blockIdx.y * 128;
    const int tid = threadIdx.x;
    const int w = tid >> 6, lane = tid & 63, q = lane >> 4, li = lane & 15;
    const int wr = w >> 1, wc = w & 1;

    const int srow = tid >> 3;
    const int cg = (tid & 7) ^ (srow & 7);
    const int ldsbase = ((tid >> 6) * 8) * 64;

    f32x4 acc[4][4];
    #pragma unroll
    for (int i = 0; i < 4; i++)
        #pragma unroll
        for (int j = 0; j < 4; j++) acc[i][j] = (f32x4){0.f, 0.f, 0.f, 0.f};

    for (int kt = 0; kt < K; kt += 64) {
        const u16* Abase;
        long lda;
        int ktA;
        if (STACK && kt >= 1024) { Abase = A2; lda = 128; ktA = kt - 1024; }
        else { Abase = A; lda = STACK ? 1024 : K; ktA = kt; }
        const u16* Ab = Abase + (long)m0 * lda + ktA + cg * 8;
        const u16* Bb = B + (long)n0 * K + kt + cg * 8;
        #pragma unroll
        for (int c = 0; c < 4; c++) {
            gload_lds16(Ab + (long)(c * 32 + srow) * lda, &As[ldsbase + c * 32 * 64]);
            gload_lds16(Bb + (long)(c * 32 + srow) * K,   &Bs[ldsbase + c * 32 * 64]);
        }
        __syncthreads();
        #pragma unroll
        for (int s = 0; s < 2; s++) {
            const int cp = ((s * 4 + q) ^ (li & 7)) * 8;
            bf16x8 av[4], bv[4];
            #pragma unroll
            for (int i = 0; i < 4; i++)
                av[i] = *(bf16x8*)&As[(wr * 64 + i * 16 + li) * 64 + cp];
            #pragma unroll
            for (int j = 0; j < 4; j++)
                bv[j] = *(bf16x8*)&Bs[(wc * 64 + j * 16 + li) * 64 + cp];
            #pragma unroll
            for (int i = 0; i < 4; i++)
                #pragma unroll
                for (int j = 0; j < 4; j++)
                    acc[i][j] = mfma16(av[i], bv[j], acc[i][j]);
        }
        __syncthreads();
    }

    #pragma unroll
    for (int i = 0; i < 4; i++) {
        #pragma unroll
        for (int j = 0; j < 4; j++) {
            const int col = n0 + wc * 64 + j * 16 + li;
            float bvs = 0.f;
            if (BIAS) bvs = bias[col];
            if (OUT_MODE == 3) {
                const int row0 = m0 + wr * 64 + i * 16 + q * 4;
                const int Lm = (1 << logL) - 1;
                long base = ((long)(((row0 >> logL) * 8 + (col >> 7)) * 128
                            + (col & 127)) << logL) + (row0 & Lm);
                u16x4 o;
                #pragma unroll
                for (int r = 0; r < 4; r++) {
                    float v = acc[i][j][r] + bvs;
                    if (RELU) v = fmaxf(v, 0.f);
                    o[r] = f2u(v);
                }
                *(u16x4*)((u16*)OutV + base) = o;
            } else {
                #pragma unroll
                for (int r = 0; r < 4; r++) {
                    const int row = m0 + wr * 64 + i * 16 + q * 4 + r;
                    float v = acc[i][j][r] + bvs;
                    if (RELU) v = fmaxf(v, 0.f);
                    long addr;
                    if (OUT_MODE == 0) {
                        addr = (long)row * ldOut + col;
                    } else if (OUT_MODE == 1) {
                        const int Lm = (1 << logL) - 1;
                        addr = ((long)((row >> logL) * 8 + (col >> 7)) << (logL + 7))
                             + ((long)(row & Lm) << 7) + (col & 127);
                    } else {
                        addr = ((long)((z >> 3) * M + row)) * 1024 + ((z & 7) << 7) + col;
                    }
                    if (OUT_F32) ((float*)OutV)[addr] = v;
                    else         ((u16*)OutV)[addr]   = f2u(v);
                }
            }
        }
    }
}

// ---------------------------------------------------------------------------
// lig AV: per bh, ONE block computes C[256 l][128 d] = att[bh] @ p2^T.
// 512 threads = 8 waves (4 m-quadrants x 2 n-halves), K=1024, both operands
// k-minor via global_load_lds + XOR chunk swizzle. att & p2t read exactly once.
// Out: lig3[((bh>>3)*256 + l)*1024 + (bh&7)*128 + d] bf16.
// ---------------------------------------------------------------------------
__global__ __launch_bounds__(512)
void ligav_kernel(const u16* __restrict__ att, const u16* __restrict__ p2t,
                  u16* __restrict__ lig3)
{
    __shared__ __align__(16) u16 As[256 * 64];
    __shared__ __align__(16) u16 Bs[128 * 64];
    const int bh = blockIdx.x;
    const u16* A = att + (long)bh * 262144;   // [256 l][1024 p]
    const u16* B = p2t + (long)bh * 131072;   // [128 d][1024 p]
    const int tid = threadIdx.x;
    const int w = tid >> 6, lane = tid & 63, q = lane >> 4, li = lane & 15;
    const int wr = w >> 1, wc = w & 1;        // wr 0..3, wc 0..1

    const int srow = tid >> 3;                 // 0..63
    const int cg = (tid & 7) ^ (srow & 7);
    const int ldsbase = ((tid >> 6) * 8) * 64; // wave-uniform

    f32x4 acc[4][4];
    #pragma unroll
    for (int i = 0; i < 4; i++)
        #pragma unroll
        for (int j = 0; j < 4; j++) acc[i][j] = (f32x4){0.f, 0.f, 0.f, 0.f};

    for (int kt = 0; kt < 1024; kt += 64) {
        const u16* Ab = A + kt + cg * 8;
        const u16* Bb = B + kt + cg * 8;
        #pragma unroll
        for (int c = 0; c < 4; c++)   // As: 256 rows, 64 rows per issue
            gload_lds16(Ab + (long)(c * 64 + srow) * 1024,
                        &As[ldsbase + c * 64 * 64]);
        #pragma unroll
        for (int c = 0; c < 2; c++)   // Bs: 128 rows
            gload_lds16(Bb + (long)(c * 64 + srow) * 1024,
                        &Bs[ldsbase + c * 64 * 64]);
        __syncthreads();
        #pragma unroll
        for (int s = 0; s < 2; s++) {
            const int cp = ((s * 4 + q) ^ (li & 7)) * 8;
            bf16x8 av[4], bv[4];
            #pragma unroll
            for (int i = 0; i < 4; i++)
                av[i] = *(bf16x8*)&As[(wr * 64 + i * 16 + li) * 64 + cp];
            #pragma unroll
            for (int j = 0; j < 4; j++)
                bv[j] = *(bf16x8*)&Bs[(wc * 64 + j * 16 + li) * 64 + cp];
            #pragma unroll
            for (int i = 0; i < 4; i++)
                #pragma unroll
                for (int j = 0; j < 4; j++)
                    acc[i][j] = mfma16(av[i], bv[j], acc[i][j]);
        }
        __syncthreads();
    }

    const long obase = ((long)(bh >> 3) * 256) * 1024 + (long)(bh & 7) * 128;
    #pragma unroll
    for (int i = 0; i < 4; i++) {
        #pragma unroll
        for (int j = 0; j < 4; j++) {
            const int col = wc * 64 + j * 16 + li;
            #pragma unroll
            for (int r = 0; r < 4; r++) {
                const int row = wr * 64 + i * 16 + q * 4 + r;
                lig3[obase + (long)row * 1024 + col] = f2u(acc[i][j][r]);
            }
        }
    }
}

// ---------------------------------------------------------------------------
// prot AV: per (m-tile of 128 p-rows, bh): C[128 p][128 d] = att^T @ l2.
// A = att[bh][l][p] (k-major -> scalar transposed staging into padded LDS),
// B = l2t[bh][d][l] (k-minor vector staging). att read exactly once.
// Out: prot3[((bh>>3)*1024 + p)*1024 + (bh&7)*128 + d] bf16.
// ---------------------------------------------------------------------------
__global__ __launch_bounds__(256)
void protav_kernel(const u16* __restrict__ att, const u16* __restrict__ l2t,
                   u16* __restrict__ prot3)
{
    __shared__ __align__(16) u16 As[128][72];
    __shared__ __align__(16) u16 Bs[128][72];
    const int bh = blockIdx.y;
    const int m0 = blockIdx.x * 128;
    const u16* A = att + (long)bh * 262144;   // [256 l][1024 p]
    const u16* B = l2t + (long)bh * 32768;    // [128 d][256 l]
    const int tid = threadIdx.x;
    const int w = tid >> 6, lane = tid & 63, q = lane >> 4, li = lane & 15;
    const int wr = w >> 1, wc = w & 1;

    f32x4 acc[4][4];
    #pragma unroll
    for (int i = 0; i < 4; i++)
        #pragma unroll
        for (int j = 0; j < 4; j++) acc[i][j] = (f32x4){0.f, 0.f, 0.f, 0.f};

    for (int kt = 0; kt < 256; kt += 64) {
        // A staging: As[m=p][k=l] = att[kt+kk][m0+mm], 16B loads along p
        #pragma unroll
        for (int h = 0; h < 4; h++) {
            const int kk = (tid >> 4) + h * 16;      // 0..63
            const int mm = (tid & 15) * 8;           // 0..120
            union { u32x4 v; u16 e[8]; } t;
            t.v = *(const u32x4*)(A + (long)(kt + kk) * 1024 + m0 + mm);
            #pragma unroll
            for (int e = 0; e < 8; e++) As[mm + e][kk] = t.e[e];
        }
        // B staging: Bs[n=d][k=l] vectorized
        #pragma unroll
        for (int h = 0; h < 2; h++) {
            const int row = (tid >> 2) + h * 64;     // 0..127
            const int cc = (tid & 3) * 16;
            const u16* src = B + (long)row * 256 + kt + cc;
            *(u32x4*)&Bs[row][cc]     = *(const u32x4*)src;
            *(u32x4*)&Bs[row][cc + 8] = *(const u32x4*)(src + 8);
        }
        __syncthreads();
        #pragma unroll
        for (int s = 0; s < 2; s++) {
            bf16x8 av[4], bv[4];
            #pragma unroll
            for (int i = 0; i < 4; i++)
                av[i] = *(bf16x8*)&As[wr * 64 + i * 16 + li][s * 32 + q * 8];
            #pragma unroll
            for (int j = 0; j < 4; j++)
                bv[j] = *(bf16x8*)&Bs[wc * 64 + j * 16 + li][s * 32 + q * 8];
            #pragma unroll
            for (int i = 0; i < 4; i++)
                #pragma unroll
                for (int j = 0; j < 4; j++)
                    acc[i][j] = mfma16(av[i], bv[j], acc[i][j]);
        }
        __syncthreads();
    }

    const long obase = ((long)(bh >> 3) * 1024 + m0) * 1024 + (long)(bh & 7) * 128;
    #pragma unroll
    for (int i = 0; i < 4; i++) {
        #pragma unroll
        for (int j = 0; j < 4; j++) {
            const int col = wc * 64 + j * 16 + li;
            #pragma unroll
            for (int r = 0; r < 4; r++) {
                const int row = wr * 64 + i * 16 + q * 4 + r;
                prot3[obase + (long)row * 1024 + col] = f2u(acc[i][j][r]);
            }
        }
    }
}

// ---------------------------------------------------------------------------
// Attention v1 (proven shape) with bf16 inter: per (m-tile 16, bh):
// S = l1 @ p1^T * inter/sqrt(128), softmax over LP=1024, write att bf16.
// ---------------------------------------------------------------------------
__global__ __launch_bounds__(256)
void attn_kernel(const u16* __restrict__ l1, const u16* __restrict__ p1,
                 const u16* __restrict__ interb, u16* __restrict__ att)
{
    __shared__ __align__(16) u16 As[16][136];
    __shared__ float wmax[4][16];
    __shared__ float wsum[4][16];
    const int bh = blockIdx.y;
    const int b  = bh >> 3;
    const int m0 = blockIdx.x * 16;
    const int tid = threadIdx.x;
    const int w = tid >> 6, lane = tid & 63, q = lane >> 4, li = lane & 15;

    {
        const int row = tid >> 4, col = (tid & 15) * 8;
        *(u32x4*)&As[row][col] =
            *(const u32x4*)(l1 + ((long)bh * 256 + m0 + row) * 128 + col);
    }
    __syncthreads();

    bf16x8 af[4];
    #pragma unroll
    for (int s = 0; s < 4; s++) af[s] = *(bf16x8*)&As[li][s * 32 + q * 8];

    float sv[16][4];
    const float rscale = 0.08838834764831845f; // 1/sqrt(128)
    for (int t = 0; t < 16; t++) {
        const int n0 = w * 256 + t * 16;
        const u16* bp = p1 + ((long)bh * 1024 + n0 + li) * 128 + q * 8;
        f32x4 acc = (f32x4){0.f, 0.f, 0.f, 0.f};
        #pragma unroll
        for (int s = 0; s < 4; s++) {
            bf16x8 bfg = *(const bf16x8*)(bp + s * 32);
            acc = mfma16(af[s], bfg, acc);
        }
        const int pcol = n0 + li;
        #pragma unroll
        for (int r = 0; r < 4; r++) {
            const int l = m0 + q * 4 + r;
            float iv = u2f(interb[((long)b * 256 + l) * 1024 + pcol]);
            sv[t][r] = acc[r] * rscale * iv;
        }
    }

    float rmax[4];
    #pragma unroll
    for (int r = 0; r < 4; r++) {
        float m = sv[0][r];
        #pragma unroll
        for (int t = 1; t < 16; t++) m = fmaxf(m, sv[t][r]);
        for (int d = 1; d < 16; d <<= 1) m = fmaxf(m, __shfl_xor(m, d, 64));
        rmax[r] = m;
    }
    if (li == 0) {
        #pragma unroll
        for (int r = 0; r < 4; r++) wmax[w][q * 4 + r] = rmax[r];
    }
    __syncthreads();
    float gmax[4];
    #pragma unroll
    for (int r = 0; r < 4; r++) {
        gmax[r] = fmaxf(fmaxf(wmax[0][q * 4 + r], wmax[1][q * 4 + r]),
                        fmaxf(wmax[2][q * 4 + r], wmax[3][q * 4 + r]));
    }
    #pragma unroll
    for (int r = 0; r < 4; r++) {
        float s = 0.f;
        #pragma unroll
        for (int t = 0; t < 16; t++) {
            float e = __expf(sv[t][r] - gmax[r]);
            sv[t][r] = e;
            s += e;
        }
        for (int d = 1; d < 16; d <<= 1) s += __shfl_xor(s, d, 64);
        if (li == 0) wsum[w][q * 4 + r] = s;
    }
    __syncthreads();
    float inv[4];
    #pragma unroll
    for (int r = 0; r < 4; r++) {
        float s = wsum[0][q * 4 + r] + wsum[1][q * 4 + r]
                + wsum[2][q * 4 + r] + wsum[3][q * 4 + r];
        inv[r] = 1.f / s;
    }
    for (int t = 0; t < 16; t++) {
        #pragma unroll
        for (int r = 0; r < 4; r++) {
            const int l = m0 + q * 4 + r;
            const int pcol = w * 256 + t * 16 + li;
            att[((long)bh * 256 + l) * 1024 + pcol] = f2u(sv[t][r] * inv[r]);
        }
    }
}

// ---------------------------------------------------------------------------
// Fused 8-way transpose + fp32->bf16 convert for weights: dst[C,R] = bf16(src^T)
// ---------------------------------------------------------------------------
struct TPF { const float* src; u16* dst; int R; int C; };
struct TPF8 { TPF t[8]; };

__global__ __launch_bounds__(256)
void cvtw_kernel(TPF8 args)
{
    TPF tp = args.t[blockIdx.z];
    const int c0 = blockIdx.x * 32, r0 = blockIdx.y * 32;
    if (c0 >= tp.C || r0 >= tp.R) return;
    __shared__ u16 tile[32][33];
    const int tx = threadIdx.x & 31, ty = threadIdx.x >> 5;
    #pragma unroll
    for (int i = 0; i < 4; i++)
        tile[ty + i * 8][tx] = f2u(tp.src[(long)(r0 + ty + i * 8) * tp.C + c0 + tx]);
    __syncthreads();
    #pragma unroll
    for (int i = 0; i < 4; i++)
        tp.dst[(long)(c0 + ty + i * 8) * tp.R + r0 + tx] = tile[tx][ty + i * 8];
}

// ---------------------------------------------------------------------------
// Weight-combine: Wst[n][0:1024] = Wout_t[n][0:128] @ Wmid_t; tail = resid W;
// bc[n] = bout[n] + bmid . Wout_t[n][0:128].
// ---------------------------------------------------------------------------
__global__ __launch_bounds__(256)
void wcomb_kernel(const u16* __restrict__ Wm0, const u16* __restrict__ Wo0,
                  const float* __restrict__ bm0, const float* __restrict__ bo0,
                  u16* __restrict__ Wst0, float* __restrict__ bc0,
                  const u16* __restrict__ Wm1, const u16* __restrict__ Wo1,
                  const float* __restrict__ bm1, const float* __restrict__ bo1,
                  u16* __restrict__ Wst1, float* __restrict__ bc1)
{
    const int zz = blockIdx.y;
    const u16* Wm = zz ? Wm1 : Wm0;
    const u16* Wo = zz ? Wo1 : Wo0;
    const float* bmid = zz ? bm1 : bm0;
    const float* bout = zz ? bo1 : bo0;
    u16* Wst = zz ? Wst1 : Wst0;
    float* bc = zz ? bc1 : bc0;
    const int n = blockIdx.x;
    const int tid = threadIdx.x;
    __shared__ float wrow[128];
    if (tid < 128) wrow[tid] = u2f(Wo[n * 256 + tid]);
    __syncthreads();
    for (int k = tid; k < 1024; k += 256) {
        float acc = 0.f;
        #pragma unroll 4
        for (int j = 0; j < 128; j++) acc += wrow[j] * u2f(Wm[(long)j * 1024 + k]);
        Wst[(long)n * 1152 + k] = f2u(acc);
    }
    if (tid < 128) Wst[(long)n * 1152 + 1024 + tid] = Wo[n * 256 + 128 + tid];
    if (tid == 0) {
        float acc = bout[n];
        for (int j = 0; j < 128; j++) acc += bmid[j] * wrow[j];
        bc[n] = acc;
    }
}

// ---------------------------------------------------------------------------
// fp32 -> bf16 converts: z=0 ligand, z=1 prot, z=2 inter
// ---------------------------------------------------------------------------
__global__ __launch_bounds__(256)
void cvt3_kernel(const float* __restrict__ a, u16* __restrict__ da, int na,
                 const float* __restrict__ b, u16* __restrict__ db, int nb,
                 const float* __restrict__ c, u16* __restrict__ dc, int nc)
{
    const int zz = blockIdx.y;
    const float* s = zz == 0 ? a : (zz == 1 ? b : c);
    u16* d = zz == 0 ? da : (zz == 1 ? db : dc);
    const int n = zz == 0 ? na : (zz == 1 ? nb : nc);
    const int i = (blockIdx.x * 256 + threadIdx.x) * 4;
    if (i >= n) return;
    const float4 v = *(const float4*)(s + i);
    u16x4 o;
    o.x = f2u(v.x); o.y = f2u(v.y); o.z = f2u(v.z); o.w = f2u(v.w);
    *(u16x4*)(d + i) = o;
}

// ---------------------------------------------------------------------------
extern "C" void kernel_launch(void* const* d_in, const int* in_sizes, int n_in,
                              void* d_out, int out_size, void* d_ws, size_t ws_size,
                              hipStream_t stream)
{
    (void)in_sizes; (void)n_in; (void)out_size; (void)ws_size;
    const float* ligand = (const float*)d_in[0];
    const float* prot   = (const float*)d_in[1];
    const float* inter  = (const float*)d_in[2];
    const float* Wl1 = (const float*)d_in[3];  const float* bl1 = (const float*)d_in[4];
    const float* Wl2 = (const float*)d_in[5];  const float* bl2 = (const float*)d_in[6];
    const float* Wp1 = (const float*)d_in[7];  const float* bp1 = (const float*)d_in[8];
    const float* Wp2 = (const float*)d_in[9];  const float* bp2 = (const float*)d_in[10];
    const float* W11 = (const float*)d_in[11]; const float* b11 = (const float*)d_in[12];
    const float* W12 = (const float*)d_in[13]; const float* b12 = (const float*)d_in[14];
    const float* W21 = (const float*)d_in[15]; const float* b21 = (const float*)d_in[16];
    const float* W22 = (const float*)d_in[17]; const float* b22 = (const float*)d_in[18];

    float* out0 = (float*)d_out;                    // [16,256,128]
    float* out1 = out0 + (size_t)16 * 256 * 128;    // [16,1024,128]

    u16* ws = (u16*)d_ws;
    size_t off = 0;
    auto alloc = [&](size_t n) { u16* p = ws + off; off += n; return p; };
    u16* ligb  = alloc(524288);    // bf16 ligand [4096,128]
    u16* protb = alloc(2097152);   // bf16 prot  [16384,128]
    u16* intb  = alloc(4194304);   // bf16 inter [16,256,1024]
    u16* l1v   = alloc(4194304);   // [16,8,256,128]
    u16* l2t   = alloc(4194304);   // [16,8,128,256]  (head-T)
    u16* p1v   = alloc(16777216);  // [16,8,1024,128]
    u16* p2t   = alloc(16777216);  // [16,8,128,1024] (head-T)
    u16* attv  = alloc(33554432);  // [16,8,256,1024]
    u16* lig3  = alloc(4194304);   // [16,256,1024]
    u16* prot3 = alloc(16777216);  // [16,1024,1024]
    u16* Wl1t  = alloc(131072);    // [1024,128]
    u16* Wl2t  = alloc(131072);
    u16* Wp1t  = alloc(131072);
    u16* Wp2t  = alloc(131072);
    u16* W11t  = alloc(131072);    // [128,1024] = W11^T
    u16* W21t  = alloc(131072);    // [128,1024] = W21^T
    u16* W12t  = alloc(32768);     // [128,256]  = W12^T
    u16* W22t  = alloc(32768);     // [128,256]  = W22^T
    u16* WstL  = alloc(147456);    // [128,1152] combined lig weight
    u16* WstP  = alloc(147456);    // [128,1152] combined prot weight
    float* bcL = (float*)alloc(256);  // [128] f32
    float* bcP = (float*)alloc(256);  // [128] f32

    // input conversion (ligand, prot, inter) -> bf16
    cvt3_kernel<<<dim3(4096, 3), 256, 0, stream>>>(
        ligand, ligb, 524288, prot, protb, 2097152, inter, intb, 4194304);

    TPF8 tp;
    tp.t[0] = {Wl1, Wl1t, 128, 1024};
    tp.t[1] = {Wl2, Wl2t, 128, 1024};
    tp.t[2] = {Wp1, Wp1t, 128, 1024};
    tp.t[3] = {Wp2, Wp2t, 128, 1024};
    tp.t[4] = {W11, W11t, 1024, 128};
    tp.t[5] = {W21, W21t, 1024, 128};
    tp.t[6] = {W12, W12t, 256, 128};
    tp.t[7] = {W22, W22t, 256, 128};
    cvtw_kernel<<<dim3(32, 32, 8), 256, 0, stream>>>(tp);

    // combine W11@W12top / W21@W22top + residual halves + biases
    wcomb_kernel<<<dim3(128, 2), 256, 0, stream>>>(
        W11t, W12t, b11, b12, WstL, bcL,
        W21t, W22t, b21, b22, WstP, bcP);

    // projections (128-tile). l1/p1 -> head layout; l2/p2 -> head-T layout.
    gemm128<1,true,true,false,false><<<dim3(8,32),256,0,stream>>>(
        ligb, nullptr, Wl1t, bl1, l1v, 4096, 1024, 128, 0, 8, 0, 0);
    gemm128<3,true,true,false,false><<<dim3(8,32),256,0,stream>>>(
        ligb, nullptr, Wl2t, bl2, l2t, 4096, 1024, 128, 0, 8, 0, 0);
    gemm128<1,true,true,false,false><<<dim3(8,128),256,0,stream>>>(
        protb, nullptr, Wp1t, bp1, p1v, 16384, 1024, 128, 0, 10, 0, 0);
    gemm128<3,true,true,false,false><<<dim3(8,128),256,0,stream>>>(
        protb, nullptr, Wp2t, bp2, p2t, 16384, 1024, 128, 0, 10, 0, 0);

    // attention scores + softmax (proven v1 shape, bf16 inter)
    attn_kernel<<<dim3(16,128),256,0,stream>>>(l1v, p1v, intb, attv);

    // lig branch: att @ p2 -> lig3 (one block per bh; att/p2t read once)
    ligav_kernel<<<dim3(128),512,0,stream>>>(attv, p2t, lig3);
    // prot branch: att^T @ l2 -> prot3 (att read once)
    protav_kernel<<<dim3(8,128),256,0,stream>>>(attv, l2t, prot3);

    // fused final: out = relu([X, resid] @ Wst^T + bc), K = 1024 + 128
    gemm128<0,true,true,true,true><<<dim3(1,32),256,0,stream>>>(
        lig3, ligb, WstL, bcL, out0, 4096, 128, 1152, 128, 0, 0, 0);
    gemm128<0,true,true,true,true><<<dim3(1,128),256,0,stream>>>(
        prot3, protb, WstP, bcP, out1, 16384, 128, 1152, 128, 0, 0, 0);
}

// Round 9
// 384.159 us; speedup vs baseline: 1.1520x; 1.0249x over previous
//
#include <hip/hip_runtime.h>
#include <hip/hip_bf16.h>

typedef unsigned short u16;
typedef __attribute__((ext_vector_type(4))) float f32x4;
typedef __attribute__((ext_vector_type(4))) unsigned int u32x4;
typedef __attribute__((ext_vector_type(4))) unsigned short u16x4;
typedef __attribute__((ext_vector_type(8))) __bf16 bf16x8;

__device__ inline float u2f(u16 u) {
    union { unsigned int i; float f; } x; x.i = ((unsigned int)u) << 16; return x.f;
}
__device__ inline u16 f2u(float f) {
    __hip_bfloat16 b = __float2bfloat16(f);
    return *reinterpret_cast<u16*>(&b);
}
__device__ inline f32x4 mfma16(bf16x8 a, bf16x8 b, f32x4 c) {
    return __builtin_amdgcn_mfma_f32_16x16x32_bf16(a, b, c, 0, 0, 0);
}
__device__ inline void gload_lds16(const u16* g, u16* l) {
    __builtin_amdgcn_global_load_lds(
        (const __attribute__((address_space(1))) unsigned int*)g,
        (__attribute__((address_space(3))) unsigned int*)l, 16, 0, 0);
}

// ---------------------------------------------------------------------------
// Merged projection GEMMs: one dispatch for all four x@W+b (relu) projections.
// grid (8, 320): y<32 lig->l1v(mode1), y<64 lig->l2t(mode3),
// y<192 prot->p1v(mode1), else prot->p2t(mode3). 128x128 tile, K=128,
// global_load_lds + XOR chunk swizzle (proven gemm128 machinery).
// ---------------------------------------------------------------------------
__global__ __launch_bounds__(256)
void proj_kernel(const u16* __restrict__ ligb, const u16* __restrict__ protb,
                 const u16* __restrict__ Wl1t, const u16* __restrict__ Wl2t,
                 const u16* __restrict__ Wp1t, const u16* __restrict__ Wp2t,
                 const float* __restrict__ bl1, const float* __restrict__ bl2,
                 const float* __restrict__ bp1, const float* __restrict__ bp2,
                 u16* __restrict__ l1v, u16* __restrict__ l2tv,
                 u16* __restrict__ p1v, u16* __restrict__ p2tv)
{
    __shared__ __align__(16) u16 As[128 * 64];
    __shared__ __align__(16) u16 Bs[128 * 64];
    const int y = blockIdx.y;
    const u16* A; const u16* B; const float* bias; u16* Out;
    int mode, logL, my;
    if (y < 32)       { A = ligb;  B = Wl1t; bias = bl1; Out = l1v;  mode = 1; logL = 8;  my = y; }
    else if (y < 64)  { A = ligb;  B = Wl2t; bias = bl2; Out = l2tv; mode = 3; logL = 8;  my = y - 32; }
    else if (y < 192) { A = protb; B = Wp1t; bias = bp1; Out = p1v;  mode = 1; logL = 10; my = y - 64; }
    else              { A = protb; B = Wp2t; bias = bp2; Out = p2tv; mode = 3; logL = 10; my = y - 192; }
    const int n0 = blockIdx.x * 128, m0 = my * 128;
    const int tid = threadIdx.x;
    const int w = tid >> 6, lane = tid & 63, q = lane >> 4, li = lane & 15;
    const int wr = w >> 1, wc = w & 1;

    const int srow = tid >> 3;
    const int cg = (tid & 7) ^ (srow & 7);
    const int ldsbase = ((tid >> 6) * 8) * 64;

    f32x4 acc[4][4];
    #pragma unroll
    for (int i = 0; i < 4; i++)
        #pragma unroll
        for (int j = 0; j < 4; j++) acc[i][j] = (f32x4){0.f, 0.f, 0.f, 0.f};

    #pragma unroll
    for (int kt = 0; kt < 128; kt += 64) {
        const u16* Ab = A + (long)m0 * 128 + kt + cg * 8;
        const u16* Bb = B + (long)n0 * 128 + kt + cg * 8;
        #pragma unroll
        for (int c = 0; c < 4; c++) {
            gload_lds16(Ab + (long)(c * 32 + srow) * 128, &As[ldsbase + c * 32 * 64]);
            gload_lds16(Bb + (long)(c * 32 + srow) * 128, &Bs[ldsbase + c * 32 * 64]);
        }
        __syncthreads();
        #pragma unroll
        for (int s = 0; s < 2; s++) {
            const int cp = ((s * 4 + q) ^ (li & 7)) * 8;
            bf16x8 av[4], bv[4];
            #pragma unroll
            for (int i = 0; i < 4; i++)
                av[i] = *(bf16x8*)&As[(wr * 64 + i * 16 + li) * 64 + cp];
            #pragma unroll
            for (int j = 0; j < 4; j++)
                bv[j] = *(bf16x8*)&Bs[(wc * 64 + j * 16 + li) * 64 + cp];
            #pragma unroll
            for (int i = 0; i < 4; i++)
                #pragma unroll
                for (int j = 0; j < 4; j++)
                    acc[i][j] = mfma16(av[i], bv[j], acc[i][j]);
        }
        __syncthreads();
    }

    const int Lm = (1 << logL) - 1;
    #pragma unroll
    for (int i = 0; i < 4; i++) {
        #pragma unroll
        for (int j = 0; j < 4; j++) {
            const int col = n0 + wc * 64 + j * 16 + li;
            const float bvs = bias[col];
            if (mode == 3) {
                const int row0 = m0 + wr * 64 + i * 16 + q * 4;
                long base = ((long)(((row0 >> logL) * 8 + (col >> 7)) * 128
                            + (col & 127)) << logL) + (row0 & Lm);
                u16x4 o;
                #pragma unroll
                for (int r = 0; r < 4; r++)
                    o[r] = f2u(fmaxf(acc[i][j][r] + bvs, 0.f));
                *(u16x4*)(Out + base) = o;
            } else {
                #pragma unroll
                for (int r = 0; r < 4; r++) {
                    const int row = m0 + wr * 64 + i * 16 + q * 4 + r;
                    long addr = ((long)((row >> logL) * 8 + (col >> 7)) << (logL + 7))
                              + ((long)(row & Lm) << 7) + (col & 127);
                    Out[addr] = f2u(fmaxf(acc[i][j][r] + bvs, 0.f));
                }
            }
        }
    }
}

// ---------------------------------------------------------------------------
// Merged AV: one dispatch. blocks [0,128): lig AV (per bh: C[256 l][128 d] =
// att[bh] @ p2^T, both k-minor via global_load_lds). blocks [128,640): prot AV
// (per (bh, p-quarter): C[256 p][128 d] = att^T @ l2, att transposed-staged).
// 512 threads = 8 waves (4 row-quadrants x 2 col-halves).
// ---------------------------------------------------------------------------
__global__ __launch_bounds__(512)
void av_kernel(const u16* __restrict__ att, const u16* __restrict__ p2t,
               const u16* __restrict__ l2t,
               u16* __restrict__ lig3, u16* __restrict__ prot3)
{
    __shared__ __align__(16) u16 As[256 * 72];
    __shared__ __align__(16) u16 Bs[128 * 72];
    const int bid = blockIdx.x;
    const int tid = threadIdx.x;
    const int w = tid >> 6, lane = tid & 63, q = lane >> 4, li = lane & 15;
    const int wr = w >> 1, wc = w & 1;     // wr 0..3 (rows), wc 0..1 (cols)

    f32x4 acc[4][4];
    #pragma unroll
    for (int i = 0; i < 4; i++)
        #pragma unroll
        for (int j = 0; j < 4; j++) acc[i][j] = (f32x4){0.f, 0.f, 0.f, 0.f};

    if (bid < 128) {
        // ---------------- lig AV ----------------
        const int bh = bid;
        const u16* A = att + (long)bh * 262144;   // [256 l][1024 p]
        const u16* B = p2t + (long)bh * 131072;   // [128 d][1024 p]
        const int srow = tid >> 3;                // 0..63
        const int cg = (tid & 7) ^ (srow & 7);
        const int ldsbase = ((tid >> 6) * 8) * 64;

        for (int kt = 0; kt < 1024; kt += 64) {
            const u16* Ab = A + kt + cg * 8;
            const u16* Bb = B + kt + cg * 8;
            #pragma unroll
            for (int c = 0; c < 4; c++)
                gload_lds16(Ab + (long)(c * 64 + srow) * 1024,
                            &As[ldsbase + c * 64 * 64]);
            #pragma unroll
            for (int c = 0; c < 2; c++)
                gload_lds16(Bb + (long)(c * 64 + srow) * 1024,
                            &Bs[ldsbase + c * 64 * 64]);
            __syncthreads();
            #pragma unroll
            for (int s = 0; s < 2; s++) {
                const int cp = ((s * 4 + q) ^ (li & 7)) * 8;
                bf16x8 av[4], bv[4];
                #pragma unroll
                for (int i = 0; i < 4; i++)
                    av[i] = *(bf16x8*)&As[(wr * 64 + i * 16 + li) * 64 + cp];
                #pragma unroll
                for (int j = 0; j < 4; j++)
                    bv[j] = *(bf16x8*)&Bs[(wc * 64 + j * 16 + li) * 64 + cp];
                #pragma unroll
                for (int i = 0; i < 4; i++)
                    #pragma unroll
                    for (int j = 0; j < 4; j++)
                        acc[i][j] = mfma16(av[i], bv[j], acc[i][j]);
            }
            __syncthreads();
        }

        const long obase = ((long)(bh >> 3) * 256) * 1024 + (long)(bh & 7) * 128;
        #pragma unroll
        for (int i = 0; i < 4; i++)
            #pragma unroll
            for (int j = 0; j < 4; j++) {
                const int col = wc * 64 + j * 16 + li;
                #pragma unroll
                for (int r = 0; r < 4; r++) {
                    const int row = wr * 64 + i * 16 + q * 4 + r;
                    lig3[obase + (long)row * 1024 + col] = f2u(acc[i][j][r]);
                }
            }
    } else {
        // ---------------- prot AV ----------------
        const int pb = bid - 128;
        const int bh = pb >> 2;
        const int m0 = (pb & 3) * 256;            // p-offset
        const u16* A = att + (long)bh * 262144;   // [256 l][1024 p]
        const u16* B = l2t + (long)bh * 32768;    // [128 d][256 l]

        for (int kt = 0; kt < 256; kt += 64) {
            // A staging: As[p][l] = att[kt+kk][m0+mm] (transposed scatter)
            #pragma unroll
            for (int h = 0; h < 4; h++) {
                const int kk = (tid >> 5) + h * 16;    // 0..63
                const int mm = (tid & 31) * 8;         // 0..248
                union { u32x4 v; u16 e[8]; } t;
                t.v = *(const u32x4*)(A + (long)(kt + kk) * 1024 + m0 + mm);
                #pragma unroll
                for (int e = 0; e < 8; e++) As[(mm + e) * 72 + kk] = t.e[e];
            }
            // B staging: Bs[d][l] vectorized
            {
                const int row = tid >> 2;              // 0..127
                const int cc = (tid & 3) * 16;
                const u16* src = B + (long)row * 256 + kt + cc;
                *(u32x4*)&Bs[row * 72 + cc]     = *(const u32x4*)src;
                *(u32x4*)&Bs[row * 72 + cc + 8] = *(const u32x4*)(src + 8);
            }
            __syncthreads();
            #pragma unroll
            for (int s = 0; s < 2; s++) {
                bf16x8 av[4], bv[4];
                #pragma unroll
                for (int i = 0; i < 4; i++)
                    av[i] = *(bf16x8*)&As[(wr * 64 + i * 16 + li) * 72 + s * 32 + q * 8];
                #pragma unroll
                for (int j = 0; j < 4; j++)
                    bv[j] = *(bf16x8*)&Bs[(wc * 64 + j * 16 + li) * 72 + s * 32 + q * 8];
                #pragma unroll
                for (int i = 0; i < 4; i++)
                    #pragma unroll
                    for (int j = 0; j < 4; j++)
                        acc[i][j] = mfma16(av[i], bv[j], acc[i][j]);
            }
            __syncthreads();
        }

        const long obase = ((long)(bh >> 3) * 1024 + m0) * 1024 + (long)(bh & 7) * 128;
        #pragma unroll
        for (int i = 0; i < 4; i++)
            #pragma unroll
            for (int j = 0; j < 4; j++) {
                const int col = wc * 64 + j * 16 + li;
                #pragma unroll
                for (int r = 0; r < 4; r++) {
                    const int row = wr * 64 + i * 16 + q * 4 + r;
                    prot3[obase + (long)row * 1024 + col] = f2u(acc[i][j][r]);
                }
            }
    }
}

// ---------------------------------------------------------------------------
// Merged finals: out = relu([X, resid] @ Wst^T + bc), K = 1024+128 (STACK).
// grid (1, 160): y<32 lig -> out0, else prot -> out1. fp32 out, ldOut=128.
// ---------------------------------------------------------------------------
__global__ __launch_bounds__(256)
void finals_kernel(const u16* __restrict__ lig3, const u16* __restrict__ ligb,
                   const u16* __restrict__ WstL, const float* __restrict__ bcL,
                   float* __restrict__ out0,
                   const u16* __restrict__ prot3, const u16* __restrict__ protb,
                   const u16* __restrict__ WstP, const float* __restrict__ bcP,
                   float* __restrict__ out1)
{
    __shared__ __align__(16) u16 As[128 * 64];
    __shared__ __align__(16) u16 Bs[128 * 64];
    const int y = blockIdx.y;
    const u16 *A, *A2, *B; const float* bias; float* Out; int my;
    if (y < 32) { A = lig3;  A2 = ligb;  B = WstL; bias = bcL; Out = out0; my = y; }
    else        { A = prot3; A2 = protb; B = WstP; bias = bcP; Out = out1; my = y - 32; }
    const int m0 = my * 128;
    const int tid = threadIdx.x;
    const int w = tid >> 6, lane = tid & 63, q = lane >> 4, li = lane & 15;
    const int wr = w >> 1, wc = w & 1;

    const int srow = tid >> 3;
    const int cg = (tid & 7) ^ (srow & 7);
    const int ldsbase = ((tid >> 6) * 8) * 64;

    f32x4 acc[4][4];
    #pragma unroll
    for (int i = 0; i < 4; i++)
        #pragma unroll
        for (int j = 0; j < 4; j++) acc[i][j] = (f32x4){0.f, 0.f, 0.f, 0.f};

    for (int kt = 0; kt < 1152; kt += 64) {
        const u16* Abase; long lda; int ktA;
        if (kt >= 1024) { Abase = A2; lda = 128; ktA = kt - 1024; }
        else            { Abase = A;  lda = 1024; ktA = kt; }
        const u16* Ab = Abase + (long)m0 * lda + ktA + cg * 8;
        const u16* Bb = B + kt + cg * 8;          // n0 = 0, ld 1152
        #pragma unroll
        for (int c = 0; c < 4; c++) {
            gload_lds16(Ab + (long)(c * 32 + srow) * lda,  &As[ldsbase + c * 32 * 64]);
            gload_lds16(Bb + (long)(c * 32 + srow) * 1152, &Bs[ldsbase + c * 32 * 64]);
        }
        __syncthreads();
        #pragma unroll
        for (int s = 0; s < 2; s++) {
            const int cp = ((s * 4 + q) ^ (li & 7)) * 8;
            bf16x8 av[4], bv[4];
            #pragma unroll
            for (int i = 0; i < 4; i++)
                av[i] = *(bf16x8*)&As[(wr * 64 + i * 16 + li) * 64 + cp];
            #pragma unroll
            for (int j = 0; j < 4; j++)
                bv[j] = *(bf16x8*)&Bs[(wc * 64 + j * 16 + li) * 64 + cp];
            #pragma unroll
            for (int i = 0; i < 4; i++)
                #pragma unroll
                for (int j = 0; j < 4; j++)
                    acc[i][j] = mfma16(av[i], bv[j], acc[i][j]);
        }
        __syncthreads();
    }

    #pragma unroll
    for (int i = 0; i < 4; i++)
        #pragma unroll
        for (int j = 0; j < 4; j++) {
            const int col = wc * 64 + j * 16 + li;
            const float bvs = bias[col];
            #pragma unroll
            for (int r = 0; r < 4; r++) {
                const int row = m0 + wr * 64 + i * 16 + q * 4 + r;
                Out[(long)row * 128 + col] = fmaxf(acc[i][j][r] + bvs, 0.f);
            }
        }
}

// ---------------------------------------------------------------------------
// Attention (R2-proven shape, fp32 inter): per (m-tile 16, bh):
// S = l1 @ p1^T * inter/sqrt(128), softmax over LP=1024, write att bf16.
// ---------------------------------------------------------------------------
__global__ __launch_bounds__(256)
void attn_kernel(const u16* __restrict__ l1, const u16* __restrict__ p1,
                 const float* __restrict__ inter, u16* __restrict__ att)
{
    __shared__ __align__(16) u16 As[16][136];
    __shared__ float wmax[4][16];
    __shared__ float wsum[4][16];
    const int bh = blockIdx.y;
    const int b  = bh >> 3;
    const int m0 = blockIdx.x * 16;
    const int tid = threadIdx.x;
    const int w = tid >> 6, lane = tid & 63, q = lane >> 4, li = lane & 15;

    {
        const int row = tid >> 4, col = (tid & 15) * 8;
        *(u32x4*)&As[row][col] =
            *(const u32x4*)(l1 + ((long)bh * 256 + m0 + row) * 128 + col);
    }
    __syncthreads();

    bf16x8 af[4];
    #pragma unroll
    for (int s = 0; s < 4; s++) af[s] = *(bf16x8*)&As[li][s * 32 + q * 8];

    float sv[16][4];
    const float rscale = 0.08838834764831845f; // 1/sqrt(128)
    for (int t = 0; t < 16; t++) {
        const int n0 = w * 256 + t * 16;
        const u16* bp = p1 + ((long)bh * 1024 + n0 + li) * 128 + q * 8;
        f32x4 acc = (f32x4){0.f, 0.f, 0.f, 0.f};
        #pragma unroll
        for (int s = 0; s < 4; s++) {
            bf16x8 bfg = *(const bf16x8*)(bp + s * 32);
            acc = mfma16(af[s], bfg, acc);
        }
        const int pcol = n0 + li;
        #pragma unroll
        for (int r = 0; r < 4; r++) {
            const int l = m0 + q * 4 + r;
            float iv = inter[((long)b * 256 + l) * 1024 + pcol];
            sv[t][r] = acc[r] * rscale * iv;
        }
    }

    float rmax[4];
    #pragma unroll
    for (int r = 0; r < 4; r++) {
        float m = sv[0][r];
        #pragma unroll
        for (int t = 1; t < 16; t++) m = fmaxf(m, sv[t][r]);
        for (int d = 1; d < 16; d <<= 1) m = fmaxf(m, __shfl_xor(m, d, 64));
        rmax[r] = m;
    }
    if (li == 0) {
        #pragma unroll
        for (int r = 0; r < 4; r++) wmax[w][q * 4 + r] = rmax[r];
    }
    __syncthreads();
    float gmax[4];
    #pragma unroll
    for (int r = 0; r < 4; r++) {
        gmax[r] = fmaxf(fmaxf(wmax[0][q * 4 + r], wmax[1][q * 4 + r]),
                        fmaxf(wmax[2][q * 4 + r], wmax[3][q * 4 + r]));
    }
    #pragma unroll
    for (int r = 0; r < 4; r++) {
        float s = 0.f;
        #pragma unroll
        for (int t = 0; t < 16; t++) {
            float e = __expf(sv[t][r] - gmax[r]);
            sv[t][r] = e;
            s += e;
        }
        for (int d = 1; d < 16; d <<= 1) s += __shfl_xor(s, d, 64);
        if (li == 0) wsum[w][q * 4 + r] = s;
    }
    __syncthreads();
    float inv[4];
    #pragma unroll
    for (int r = 0; r < 4; r++) {
        float s = wsum[0][q * 4 + r] + wsum[1][q * 4 + r]
                + wsum[2][q * 4 + r] + wsum[3][q * 4 + r];
        inv[r] = 1.f / s;
    }
    for (int t = 0; t < 16; t++) {
        #pragma unroll
        for (int r = 0; r < 4; r++) {
            const int l = m0 + q * 4 + r;
            const int pcol = w * 256 + t * 16 + li;
            att[((long)bh * 256 + l) * 1024 + pcol] = f2u(sv[t][r] * inv[r]);
        }
    }
}

// ---------------------------------------------------------------------------
// Fused 8-way transpose + fp32->bf16 convert for weights: dst[C,R] = bf16(src^T)
// ---------------------------------------------------------------------------
struct TPF { const float* src; u16* dst; int R; int C; };
struct TPF8 { TPF t[8]; };

__global__ __launch_bounds__(256)
void cvtw_kernel(TPF8 args)
{
    TPF tp = args.t[blockIdx.z];
    const int c0 = blockIdx.x * 32, r0 = blockIdx.y * 32;
    if (c0 >= tp.C || r0 >= tp.R) return;
    __shared__ u16 tile[32][33];
    const int tx = threadIdx.x & 31, ty = threadIdx.x >> 5;
    #pragma unroll
    for (int i = 0; i < 4; i++)
        tile[ty + i * 8][tx] = f2u(tp.src[(long)(r0 + ty + i * 8) * tp.C + c0 + tx]);
    __syncthreads();
    #pragma unroll
    for (int i = 0; i < 4; i++)
        tp.dst[(long)(c0 + ty + i * 8) * tp.R + r0 + tx] = tile[tx][ty + i * 8];
}

// ---------------------------------------------------------------------------
// Weight-combine: Wst[n][0:1024] = Wout_t[n][0:128] @ Wmid_t; tail = resid W;
// bc[n] = bout[n] + bmid . Wout_t[n][0:128].
// ---------------------------------------------------------------------------
__global__ __launch_bounds__(256)
void wcomb_kernel(const u16* __restrict__ Wm0, const u16* __restrict__ Wo0,
                  const float* __restrict__ bm0, const float* __restrict__ bo0,
                  u16* __restrict__ Wst0, float* __restrict__ bc0,
                  const u16* __restrict__ Wm1, const u16* __restrict__ Wo1,
                  const float* __restrict__ bm1, const float* __restrict__ bo1,
                  u16* __restrict__ Wst1, float* __restrict__ bc1)
{
    const int zz = blockIdx.y;
    const u16* Wm = zz ? Wm1 : Wm0;
    const u16* Wo = zz ? Wo1 : Wo0;
    const float* bmid = zz ? bm1 : bm0;
    const float* bout = zz ? bo1 : bo0;
    u16* Wst = zz ? Wst1 : Wst0;
    float* bc = zz ? bc1 : bc0;
    const int n = blockIdx.x;
    const int tid = threadIdx.x;
    __shared__ float wrow[128];
    if (tid < 128) wrow[tid] = u2f(Wo[n * 256 + tid]);
    __syncthreads();
    for (int k = tid; k < 1024; k += 256) {
        float acc = 0.f;
        #pragma unroll 4
        for (int j = 0; j < 128; j++) acc += wrow[j] * u2f(Wm[(long)j * 1024 + k]);
        Wst[(long)n * 1152 + k] = f2u(acc);
    }
    if (tid < 128) Wst[(long)n * 1152 + 1024 + tid] = Wo[n * 256 + 128 + tid];
    if (tid == 0) {
        float acc = bout[n];
        for (int j = 0; j < 128; j++) acc += bmid[j] * wrow[j];
        bc[n] = acc;
    }
}

// ---------------------------------------------------------------------------
// fp32 -> bf16 converts: z=0 ligand, z=1 prot (inter stays fp32!)
// ---------------------------------------------------------------------------
__global__ __launch_bounds__(256)
void cvt2_kernel(const float* __restrict__ a, u16* __restrict__ da, int na,
                 const float* __restrict__ b, u16* __restrict__ db, int nb)
{
    const int zz = blockIdx.y;
    const float* s = zz ? b : a;
    u16* d = zz ? db : da;
    const int n = zz ? nb : na;
    const int i = (blockIdx.x * 256 + threadIdx.x) * 4;
    if (i >= n) return;
    const float4 v = *(const float4*)(s + i);
    u16x4 o;
    o.x = f2u(v.x); o.y = f2u(v.y); o.z = f2u(v.z); o.w = f2u(v.w);
    *(u16x4*)(d + i) = o;
}

// ---------------------------------------------------------------------------
extern "C" void kernel_launch(void* const* d_in, const int* in_sizes, int n_in,
                              void* d_out, int out_size, void* d_ws, size_t ws_size,
                              hipStream_t stream)
{
    (void)in_sizes; (void)n_in; (void)out_size; (void)ws_size;
    const float* ligand = (const float*)d_in[0];
    const float* prot   = (const float*)d_in[1];
    const float* inter  = (const float*)d_in[2];
    const float* Wl1 = (const float*)d_in[3];  const float* bl1 = (const float*)d_in[4];
    const float* Wl2 = (const float*)d_in[5];  const float* bl2 = (const float*)d_in[6];
    const float* Wp1 = (const float*)d_in[7];  const float* bp1 = (const float*)d_in[8];
    const float* Wp2 = (const float*)d_in[9];  const float* bp2 = (const float*)d_in[10];
    const float* W11 = (const float*)d_in[11]; const float* b11 = (const float*)d_in[12];
    const float* W12 = (const float*)d_in[13]; const float* b12 = (const float*)d_in[14];
    const float* W21 = (const float*)d_in[15]; const float* b21 = (const float*)d_in[16];
    const float* W22 = (const float*)d_in[17]; const float* b22 = (const float*)d_in[18];

    float* out0 = (float*)d_out;                    // [16,256,128]
    float* out1 = out0 + (size_t)16 * 256 * 128;    // [16,1024,128]

    u16* ws = (u16*)d_ws;
    size_t off = 0;
    auto alloc = [&](size_t n) { u16* p = ws + off; off += n; return p; };
    u16* ligb  = alloc(524288);    // bf16 ligand [4096,128]
    u16* protb = alloc(2097152);   // bf16 prot  [16384,128]
    u16* l1v   = alloc(4194304);   // [16,8,256,128]
    u16* l2t   = alloc(4194304);   // [16,8,128,256]  (head-T)
    u16* p1v   = alloc(16777216);  // [16,8,1024,128]
    u16* p2t   = alloc(16777216);  // [16,8,128,1024] (head-T)
    u16* attv  = alloc(33554432);  // [16,8,256,1024]
    u16* lig3  = alloc(4194304);   // [16,256,1024]
    u16* prot3 = alloc(16777216);  // [16,1024,1024]
    u16* Wl1t  = alloc(131072);    // [1024,128]
    u16* Wl2t  = alloc(131072);
    u16* Wp1t  = alloc(131072);
    u16* Wp2t  = alloc(131072);
    u16* W11t  = alloc(131072);    // [128,1024] = W11^T
    u16* W21t  = alloc(131072);    // [128,1024] = W21^T
    u16* W12t  = alloc(32768);     // [128,256]  = W12^T
    u16* W22t  = alloc(32768);     // [128,256]  = W22^T
    u16* WstL  = alloc(147456);    // [128,1152] combined lig weight
    u16* WstP  = alloc(147456);    // [128,1152] combined prot weight
    float* bcL = (float*)alloc(256);  // [128] f32
    float* bcP = (float*)alloc(256);  // [128] f32

    // input conversion (ligand, prot) -> bf16; inter stays fp32
    cvt2_kernel<<<dim3(2048, 2), 256, 0, stream>>>(
        ligand, ligb, 524288, prot, protb, 2097152);

    TPF8 tp;
    tp.t[0] = {Wl1, Wl1t, 128, 1024};
    tp.t[1] = {Wl2, Wl2t, 128, 1024};
    tp.t[2] = {Wp1, Wp1t, 128, 1024};
    tp.t[3] = {Wp2, Wp2t, 128, 1024};
    tp.t[4] = {W11, W11t, 1024, 128};
    tp.t[5] = {W21, W21t, 1024, 128};
    tp.t[6] = {W12, W12t, 256, 128};
    tp.t[7] = {W22, W22t, 256, 128};
    cvtw_kernel<<<dim3(32, 32, 8), 256, 0, stream>>>(tp);

    // combine W11@W12top / W21@W22top + residual halves + biases
    wcomb_kernel<<<dim3(128, 2), 256, 0, stream>>>(
        W11t, W12t, b11, b12, WstL, bcL,
        W21t, W22t, b21, b22, WstP, bcP);

    // all four projections in one dispatch
    proj_kernel<<<dim3(8, 320), 256, 0, stream>>>(
        ligb, protb, Wl1t, Wl2t, Wp1t, Wp2t,
        bl1, bl2, bp1, bp2, l1v, l2t, p1v, p2t);

    // attention scores + softmax (fp32 inter, proven shape)
    attn_kernel<<<dim3(16, 128), 256, 0, stream>>>(l1v, p1v, inter, attv);

    // both AV GEMMs in one dispatch (lig blocks + prot blocks co-resident)
    av_kernel<<<dim3(640), 512, 0, stream>>>(attv, p2t, l2t, lig3, prot3);

    // both fused finals in one dispatch
    finals_kernel<<<dim3(1, 160), 256, 0, stream>>>(
        lig3, ligb, WstL, bcL, out0,
        prot3, protb, WstP, bcP, out1);
}

// Round 10
// 328.033 us; speedup vs baseline: 1.3491x; 1.1711x over previous
//
#include <hip/hip_runtime.h>
#include <hip/hip_bf16.h>

typedef unsigned short u16;
typedef __attribute__((ext_vector_type(4))) float f32x4;
typedef __attribute__((ext_vector_type(4))) unsigned int u32x4;
typedef __attribute__((ext_vector_type(4))) unsigned short u16x4;
typedef __attribute__((ext_vector_type(8))) __bf16 bf16x8;

__device__ inline float u2f(u16 u) {
    union { unsigned int i; float f; } x; x.i = ((unsigned int)u) << 16; return x.f;
}
__device__ inline u16 f2u(float f) {
    __hip_bfloat16 b = __float2bfloat16(f);
    return *reinterpret_cast<u16*>(&b);
}
__device__ inline f32x4 mfma16(bf16x8 a, bf16x8 b, f32x4 c) {
    return __builtin_amdgcn_mfma_f32_16x16x32_bf16(a, b, c, 0, 0, 0);
}
__device__ inline void gload_lds16(const u16* g, u16* l) {
    __builtin_amdgcn_global_load_lds(
        (const __attribute__((address_space(1))) unsigned int*)g,
        (__attribute__((address_space(3))) unsigned int*)l, 16, 0, 0);
}

// ---------------------------------------------------------------------------
// Merged projection GEMMs: one dispatch for all four x@W+b (relu) projections.
// grid (8, 320): y<32 lig->l1v(mode1), y<64 lig->l2t(mode3),
// y<192 prot->p1v(mode1), else prot->p2t(mode3). 128x128 tile, K=128.
// ---------------------------------------------------------------------------
__global__ __launch_bounds__(256)
void proj_kernel(const u16* __restrict__ ligb, const u16* __restrict__ protb,
                 const u16* __restrict__ Wl1t, const u16* __restrict__ Wl2t,
                 const u16* __restrict__ Wp1t, const u16* __restrict__ Wp2t,
                 const float* __restrict__ bl1, const float* __restrict__ bl2,
                 const float* __restrict__ bp1, const float* __restrict__ bp2,
                 u16* __restrict__ l1v, u16* __restrict__ l2tv,
                 u16* __restrict__ p1v, u16* __restrict__ p2tv)
{
    __shared__ __align__(16) u16 As[128 * 64];
    __shared__ __align__(16) u16 Bs[128 * 64];
    const int y = blockIdx.y;
    const u16* A; const u16* B; const float* bias; u16* Out;
    int mode, logL, my;
    if (y < 32)       { A = ligb;  B = Wl1t; bias = bl1; Out = l1v;  mode = 1; logL = 8;  my = y; }
    else if (y < 64)  { A = ligb;  B = Wl2t; bias = bl2; Out = l2tv; mode = 3; logL = 8;  my = y - 32; }
    else if (y < 192) { A = protb; B = Wp1t; bias = bp1; Out = p1v;  mode = 1; logL = 10; my = y - 64; }
    else              { A = protb; B = Wp2t; bias = bp2; Out = p2tv; mode = 3; logL = 10; my = y - 192; }
    const int n0 = blockIdx.x * 128, m0 = my * 128;
    const int tid = threadIdx.x;
    const int w = tid >> 6, lane = tid & 63, q = lane >> 4, li = lane & 15;
    const int wr = w >> 1, wc = w & 1;

    const int srow = tid >> 3;
    const int cg = (tid & 7) ^ (srow & 7);
    const int ldsbase = ((tid >> 6) * 8) * 64;

    f32x4 acc[4][4];
    #pragma unroll
    for (int i = 0; i < 4; i++)
        #pragma unroll
        for (int j = 0; j < 4; j++) acc[i][j] = (f32x4){0.f, 0.f, 0.f, 0.f};

    #pragma unroll
    for (int kt = 0; kt < 128; kt += 64) {
        const u16* Ab = A + (long)m0 * 128 + kt + cg * 8;
        const u16* Bb = B + (long)n0 * 128 + kt + cg * 8;
        #pragma unroll
        for (int c = 0; c < 4; c++) {
            gload_lds16(Ab + (long)(c * 32 + srow) * 128, &As[ldsbase + c * 32 * 64]);
            gload_lds16(Bb + (long)(c * 32 + srow) * 128, &Bs[ldsbase + c * 32 * 64]);
        }
        __syncthreads();
        #pragma unroll
        for (int s = 0; s < 2; s++) {
            const int cp = ((s * 4 + q) ^ (li & 7)) * 8;
            bf16x8 av[4], bv[4];
            #pragma unroll
            for (int i = 0; i < 4; i++)
                av[i] = *(bf16x8*)&As[(wr * 64 + i * 16 + li) * 64 + cp];
            #pragma unroll
            for (int j = 0; j < 4; j++)
                bv[j] = *(bf16x8*)&Bs[(wc * 64 + j * 16 + li) * 64 + cp];
            #pragma unroll
            for (int i = 0; i < 4; i++)
                #pragma unroll
                for (int j = 0; j < 4; j++)
                    acc[i][j] = mfma16(av[i], bv[j], acc[i][j]);
        }
        __syncthreads();
    }

    const int Lm = (1 << logL) - 1;
    #pragma unroll
    for (int i = 0; i < 4; i++) {
        #pragma unroll
        for (int j = 0; j < 4; j++) {
            const int col = n0 + wc * 64 + j * 16 + li;
            const float bvs = bias[col];
            if (mode == 3) {
                const int row0 = m0 + wr * 64 + i * 16 + q * 4;
                long base = ((long)(((row0 >> logL) * 8 + (col >> 7)) * 128
                            + (col & 127)) << logL) + (row0 & Lm);
                u16x4 o;
                #pragma unroll
                for (int r = 0; r < 4; r++)
                    o[r] = f2u(fmaxf(acc[i][j][r] + bvs, 0.f));
                *(u16x4*)(Out + base) = o;
            } else {
                #pragma unroll
                for (int r = 0; r < 4; r++) {
                    const int row = m0 + wr * 64 + i * 16 + q * 4 + r;
                    long addr = ((long)((row >> logL) * 8 + (col >> 7)) << (logL + 7))
                              + ((long)(row & Lm) << 7) + (col & 127);
                    Out[addr] = f2u(fmaxf(acc[i][j][r] + bvs, 0.f));
                }
            }
        }
    }
}

// ---------------------------------------------------------------------------
// Merged AV: blocks [0,128): lig AV (per bh: C[256 l][128 d] = att @ p2^T,
// both k-minor via global_load_lds). blocks [128,640): prot AV (per
// (bh, p-quarter): C[256 p][128 d] = att^T @ l2) with CONFLICT-FREE two-stage
// transpose: stage1 gload att tile -> T[64 l][256 p] (HW-contiguous, no
// conflicts); stage2 per-wave LDS transpose T -> XOR-swizzled As[256 p][64 l]
// (reads: lanes along p = conflict-free; writes: 4 b128/thread/kt);
// stage3 MFMA reads XOR pattern (proven clean). B via gload+XOR.
// 512 threads = 8 waves (4 row-quadrants x 2 col-halves).
// ---------------------------------------------------------------------------
__global__ __launch_bounds__(512)
void av_kernel(const u16* __restrict__ att, const u16* __restrict__ p2t,
               const u16* __restrict__ l2t,
               u16* __restrict__ lig3, u16* __restrict__ prot3)
{
    __shared__ __align__(16) u16 As[256 * 64];   // 32 KB
    __shared__ __align__(16) u16 Bs[128 * 64];   // 16 KB
    __shared__ __align__(16) u16 T[64 * 256];    // 32 KB (prot stage-1 tile)
    const int bid = blockIdx.x;
    const int tid = threadIdx.x;
    const int w = tid >> 6, lane = tid & 63, q = lane >> 4, li = lane & 15;
    const int wr = w >> 1, wc = w & 1;     // wr 0..3 (rows), wc 0..1 (cols)

    f32x4 acc[4][4];
    #pragma unroll
    for (int i = 0; i < 4; i++)
        #pragma unroll
        for (int j = 0; j < 4; j++) acc[i][j] = (f32x4){0.f, 0.f, 0.f, 0.f};

    if (bid < 128) {
        // ---------------- lig AV ----------------
        const int bh = bid;
        const u16* A = att + (long)bh * 262144;   // [256 l][1024 p]
        const u16* B = p2t + (long)bh * 131072;   // [128 d][1024 p]
        const int srow = tid >> 3;                // 0..63
        const int cg = (tid & 7) ^ (srow & 7);
        const int ldsbase = ((tid >> 6) * 8) * 64;

        for (int kt = 0; kt < 1024; kt += 64) {
            const u16* Ab = A + kt + cg * 8;
            const u16* Bb = B + kt + cg * 8;
            #pragma unroll
            for (int c = 0; c < 4; c++)
                gload_lds16(Ab + (long)(c * 64 + srow) * 1024,
                            &As[ldsbase + c * 64 * 64]);
            #pragma unroll
            for (int c = 0; c < 2; c++)
                gload_lds16(Bb + (long)(c * 64 + srow) * 1024,
                            &Bs[ldsbase + c * 64 * 64]);
            __syncthreads();
            #pragma unroll
            for (int s = 0; s < 2; s++) {
                const int cp = ((s * 4 + q) ^ (li & 7)) * 8;
                bf16x8 av[4], bv[4];
                #pragma unroll
                for (int i = 0; i < 4; i++)
                    av[i] = *(bf16x8*)&As[(wr * 64 + i * 16 + li) * 64 + cp];
                #pragma unroll
                for (int j = 0; j < 4; j++)
                    bv[j] = *(bf16x8*)&Bs[(wc * 64 + j * 16 + li) * 64 + cp];
                #pragma unroll
                for (int i = 0; i < 4; i++)
                    #pragma unroll
                    for (int j = 0; j < 4; j++)
                        acc[i][j] = mfma16(av[i], bv[j], acc[i][j]);
            }
            __syncthreads();
        }

        const long obase = ((long)(bh >> 3) * 256) * 1024 + (long)(bh & 7) * 128;
        #pragma unroll
        for (int i = 0; i < 4; i++)
            #pragma unroll
            for (int j = 0; j < 4; j++) {
                const int col = wc * 64 + j * 16 + li;
                #pragma unroll
                for (int r = 0; r < 4; r++) {
                    const int row = wr * 64 + i * 16 + q * 4 + r;
                    lig3[obase + (long)row * 1024 + col] = f2u(acc[i][j][r]);
                }
            }
    } else {
        // ---------------- prot AV ----------------
        const int pb = bid - 128;
        const int bh = pb >> 2;
        const int m0 = (pb & 3) * 256;            // p-offset
        const u16* A = att + (long)bh * 262144;   // [256 l][1024 p]
        const u16* B = l2t + (long)bh * 32768;    // [128 d][256 l]
        const int w6 = tid >> 6;                  // wave id 0..7
        const int i5 = (tid >> 5) & 1;
        const int srow = tid >> 3;                // 0..63 (B staging)
        const int cg = (tid & 7) ^ (srow & 7);
        const int bldsbase = w6 * 8 * 64;

        for (int kt = 0; kt < 256; kt += 64) {
            // stage 1: gload att rows [kt, kt+64) x p [m0, m0+256) -> T[l][p]
            // wave w covers T rows w*8 .. w*8+7 (contiguous flat segments)
            #pragma unroll
            for (int c = 0; c < 4; c++) {
                gload_lds16(A + (long)(kt + w6 * 8 + c * 2 + i5) * 1024
                              + m0 + (tid & 31) * 8,
                            &T[w6 * 2048 + c * 512]);
            }
            // B staging: l2t k-minor via gload + XOR
            #pragma unroll
            for (int c = 0; c < 2; c++)
                gload_lds16(B + (long)(c * 64 + srow) * 256 + kt + cg * 8,
                            &Bs[bldsbase + c * 64 * 64]);
            __syncthreads();

            // stage 2: transpose T -> As (XOR chunk swizzle).
            // wave w owns l-chunk w; lanes along p (conflict-free reads).
            #pragma unroll
            for (int pass = 0; pass < 4; pass++) {
                const int p = pass * 64 + (tid & 63);
                union { u16 e[8]; u32x4 v; } tmp;
                #pragma unroll
                for (int e = 0; e < 8; e++)
                    tmp.e[e] = T[(w6 * 8 + e) * 256 + p];
                *(u32x4*)&As[p * 64 + ((w6 ^ (p & 7)) * 8)] = tmp.v;
            }
            __syncthreads();

            // stage 3: MFMA (XOR reads, proven conflict-free)
            #pragma unroll
            for (int s = 0; s < 2; s++) {
                const int cp = ((s * 4 + q) ^ (li & 7)) * 8;
                bf16x8 av[4], bv[4];
                #pragma unroll
                for (int i = 0; i < 4; i++)
                    av[i] = *(bf16x8*)&As[(wr * 64 + i * 16 + li) * 64 + cp];
                #pragma unroll
                for (int j = 0; j < 4; j++)
                    bv[j] = *(bf16x8*)&Bs[(wc * 64 + j * 16 + li) * 64 + cp];
                #pragma unroll
                for (int i = 0; i < 4; i++)
                    #pragma unroll
                    for (int j = 0; j < 4; j++)
                        acc[i][j] = mfma16(av[i], bv[j], acc[i][j]);
            }
            __syncthreads();
        }

        const long obase = ((long)(bh >> 3) * 1024 + m0) * 1024 + (long)(bh & 7) * 128;
        #pragma unroll
        for (int i = 0; i < 4; i++)
            #pragma unroll
            for (int j = 0; j < 4; j++) {
                const int col = wc * 64 + j * 16 + li;
                #pragma unroll
                for (int r = 0; r < 4; r++) {
                    const int row = wr * 64 + i * 16 + q * 4 + r;
                    prot3[obase + (long)row * 1024 + col] = f2u(acc[i][j][r]);
                }
            }
    }
}

// ---------------------------------------------------------------------------
// Merged finals: out = relu([X, resid] @ Wst^T + bc), K = 1024+128 (STACK).
// grid (1, 160): y<32 lig -> out0, else prot -> out1. fp32 out, ldOut=128.
// ---------------------------------------------------------------------------
__global__ __launch_bounds__(256)
void finals_kernel(const u16* __restrict__ lig3, const u16* __restrict__ ligb,
                   const u16* __restrict__ WstL, const float* __restrict__ bcL,
                   float* __restrict__ out0,
                   const u16* __restrict__ prot3, const u16* __restrict__ protb,
                   const u16* __restrict__ WstP, const float* __restrict__ bcP,
                   float* __restrict__ out1)
{
    __shared__ __align__(16) u16 As[128 * 64];
    __shared__ __align__(16) u16 Bs[128 * 64];
    const int y = blockIdx.y;
    const u16 *A, *A2, *B; const float* bias; float* Out; int my;
    if (y < 32) { A = lig3;  A2 = ligb;  B = WstL; bias = bcL; Out = out0; my = y; }
    else        { A = prot3; A2 = protb; B = WstP; bias = bcP; Out = out1; my = y - 32; }
    const int m0 = my * 128;
    const int tid = threadIdx.x;
    const int w = tid >> 6, lane = tid & 63, q = lane >> 4, li = lane & 15;
    const int wr = w >> 1, wc = w & 1;

    const int srow = tid >> 3;
    const int cg = (tid & 7) ^ (srow & 7);
    const int ldsbase = ((tid >> 6) * 8) * 64;

    f32x4 acc[4][4];
    #pragma unroll
    for (int i = 0; i < 4; i++)
        #pragma unroll
        for (int j = 0; j < 4; j++) acc[i][j] = (f32x4){0.f, 0.f, 0.f, 0.f};

    for (int kt = 0; kt < 1152; kt += 64) {
        const u16* Abase; long lda; int ktA;
        if (kt >= 1024) { Abase = A2; lda = 128; ktA = kt - 1024; }
        else            { Abase = A;  lda = 1024; ktA = kt; }
        const u16* Ab = Abase + (long)m0 * lda + ktA + cg * 8;
        const u16* Bb = B + kt + cg * 8;          // n0 = 0, ld 1152
        #pragma unroll
        for (int c = 0; c < 4; c++) {
            gload_lds16(Ab + (long)(c * 32 + srow) * lda,  &As[ldsbase + c * 32 * 64]);
            gload_lds16(Bb + (long)(c * 32 + srow) * 1152, &Bs[ldsbase + c * 32 * 64]);
        }
        __syncthreads();
        #pragma unroll
        for (int s = 0; s < 2; s++) {
            const int cp = ((s * 4 + q) ^ (li & 7)) * 8;
            bf16x8 av[4], bv[4];
            #pragma unroll
            for (int i = 0; i < 4; i++)
                av[i] = *(bf16x8*)&As[(wr * 64 + i * 16 + li) * 64 + cp];
            #pragma unroll
            for (int j = 0; j < 4; j++)
                bv[j] = *(bf16x8*)&Bs[(wc * 64 + j * 16 + li) * 64 + cp];
            #pragma unroll
            for (int i = 0; i < 4; i++)
                #pragma unroll
                for (int j = 0; j < 4; j++)
                    acc[i][j] = mfma16(av[i], bv[j], acc[i][j]);
        }
        __syncthreads();
    }

    #pragma unroll
    for (int i = 0; i < 4; i++)
        #pragma unroll
        for (int j = 0; j < 4; j++) {
            const int col = wc * 64 + j * 16 + li;
            const float bvs = bias[col];
            #pragma unroll
            for (int r = 0; r < 4; r++) {
                const int row = m0 + wr * 64 + i * 16 + q * 4 + r;
                Out[(long)row * 128 + col] = fmaxf(acc[i][j][r] + bvs, 0.f);
            }
        }
}

// ---------------------------------------------------------------------------
// Attention (proven shape, fp32 inter): per (m-tile 16, bh):
// S = l1 @ p1^T * inter/sqrt(128), softmax over LP=1024, write att bf16.
// ---------------------------------------------------------------------------
__global__ __launch_bounds__(256)
void attn_kernel(const u16* __restrict__ l1, const u16* __restrict__ p1,
                 const float* __restrict__ inter, u16* __restrict__ att)
{
    __shared__ __align__(16) u16 As[16][136];
    __shared__ float wmax[4][16];
    __shared__ float wsum[4][16];
    const int bh = blockIdx.y;
    const int b  = bh >> 3;
    const int m0 = blockIdx.x * 16;
    const int tid = threadIdx.x;
    const int w = tid >> 6, lane = tid & 63, q = lane >> 4, li = lane & 15;

    {
        const int row = tid >> 4, col = (tid & 15) * 8;
        *(u32x4*)&As[row][col] =
            *(const u32x4*)(l1 + ((long)bh * 256 + m0 + row) * 128 + col);
    }
    __syncthreads();

    bf16x8 af[4];
    #pragma unroll
    for (int s = 0; s < 4; s++) af[s] = *(bf16x8*)&As[li][s * 32 + q * 8];

    float sv[16][4];
    const float rscale = 0.08838834764831845f; // 1/sqrt(128)
    for (int t = 0; t < 16; t++) {
        const int n0 = w * 256 + t * 16;
        const u16* bp = p1 + ((long)bh * 1024 + n0 + li) * 128 + q * 8;
        f32x4 acc = (f32x4){0.f, 0.f, 0.f, 0.f};
        #pragma unroll
        for (int s = 0; s < 4; s++) {
            bf16x8 bfg = *(const bf16x8*)(bp + s * 32);
            acc = mfma16(af[s], bfg, acc);
        }
        const int pcol = n0 + li;
        #pragma unroll
        for (int r = 0; r < 4; r++) {
            const int l = m0 + q * 4 + r;
            float iv = inter[((long)b * 256 + l) * 1024 + pcol];
            sv[t][r] = acc[r] * rscale * iv;
        }
    }

    float rmax[4];
    #pragma unroll
    for (int r = 0; r < 4; r++) {
        float m = sv[0][r];
        #pragma unroll
        for (int t = 1; t < 16; t++) m = fmaxf(m, sv[t][r]);
        for (int d = 1; d < 16; d <<= 1) m = fmaxf(m, __shfl_xor(m, d, 64));
        rmax[r] = m;
    }
    if (li == 0) {
        #pragma unroll
        for (int r = 0; r < 4; r++) wmax[w][q * 4 + r] = rmax[r];
    }
    __syncthreads();
    float gmax[4];
    #pragma unroll
    for (int r = 0; r < 4; r++) {
        gmax[r] = fmaxf(fmaxf(wmax[0][q * 4 + r], wmax[1][q * 4 + r]),
                        fmaxf(wmax[2][q * 4 + r], wmax[3][q * 4 + r]));
    }
    #pragma unroll
    for (int r = 0; r < 4; r++) {
        float s = 0.f;
        #pragma unroll
        for (int t = 0; t < 16; t++) {
            float e = __expf(sv[t][r] - gmax[r]);
            sv[t][r] = e;
            s += e;
        }
        for (int d = 1; d < 16; d <<= 1) s += __shfl_xor(s, d, 64);
        if (li == 0) wsum[w][q * 4 + r] = s;
    }
    __syncthreads();
    float inv[4];
    #pragma unroll
    for (int r = 0; r < 4; r++) {
        float s = wsum[0][q * 4 + r] + wsum[1][q * 4 + r]
                + wsum[2][q * 4 + r] + wsum[3][q * 4 + r];
        inv[r] = 1.f / s;
    }
    for (int t = 0; t < 16; t++) {
        #pragma unroll
        for (int r = 0; r < 4; r++) {
            const int l = m0 + q * 4 + r;
            const int pcol = w * 256 + t * 16 + li;
            att[((long)bh * 256 + l) * 1024 + pcol] = f2u(sv[t][r] * inv[r]);
        }
    }
}

// ---------------------------------------------------------------------------
// Fused 8-way transpose + fp32->bf16 convert for weights: dst[C,R] = bf16(src^T)
// ---------------------------------------------------------------------------
struct TPF { const float* src; u16* dst; int R; int C; };
struct TPF8 { TPF t[8]; };

__global__ __launch_bounds__(256)
void cvtw_kernel(TPF8 args)
{
    TPF tp = args.t[blockIdx.z];
    const int c0 = blockIdx.x * 32, r0 = blockIdx.y * 32;
    if (c0 >= tp.C || r0 >= tp.R) return;
    __shared__ u16 tile[32][33];
    const int tx = threadIdx.x & 31, ty = threadIdx.x >> 5;
    #pragma unroll
    for (int i = 0; i < 4; i++)
        tile[ty + i * 8][tx] = f2u(tp.src[(long)(r0 + ty + i * 8) * tp.C + c0 + tx]);
    __syncthreads();
    #pragma unroll
    for (int i = 0; i < 4; i++)
        tp.dst[(long)(c0 + ty + i * 8) * tp.R + r0 + tx] = tile[tx][ty + i * 8];
}

// ---------------------------------------------------------------------------
// Weight-combine: Wst[n][0:1024] = Wout_t[n][0:128] @ Wmid_t; tail = resid W;
// bc[n] = bout[n] + bmid . Wout_t[n][0:128].
// ---------------------------------------------------------------------------
__global__ __launch_bounds__(256)
void wcomb_kernel(const u16* __restrict__ Wm0, const u16* __restrict__ Wo0,
                  const float* __restrict__ bm0, const float* __restrict__ bo0,
                  u16* __restrict__ Wst0, float* __restrict__ bc0,
                  const u16* __restrict__ Wm1, const u16* __restrict__ Wo1,
                  const float* __restrict__ bm1, const float* __restrict__ bo1,
                  u16* __restrict__ Wst1, float* __restrict__ bc1)
{
    const int zz = blockIdx.y;
    const u16* Wm = zz ? Wm1 : Wm0;
    const u16* Wo = zz ? Wo1 : Wo0;
    const float* bmid = zz ? bm1 : bm0;
    const float* bout = zz ? bo1 : bo0;
    u16* Wst = zz ? Wst1 : Wst0;
    float* bc = zz ? bc1 : bc0;
    const int n = blockIdx.x;
    const int tid = threadIdx.x;
    __shared__ float wrow[128];
    if (tid < 128) wrow[tid] = u2f(Wo[n * 256 + tid]);
    __syncthreads();
    for (int k = tid; k < 1024; k += 256) {
        float acc = 0.f;
        #pragma unroll 4
        for (int j = 0; j < 128; j++) acc += wrow[j] * u2f(Wm[(long)j * 1024 + k]);
        Wst[(long)n * 1152 + k] = f2u(acc);
    }
    if (tid < 128) Wst[(long)n * 1152 + 1024 + tid] = Wo[n * 256 + 128 + tid];
    if (tid == 0) {
        float acc = bout[n];
        for (int j = 0; j < 128; j++) acc += bmid[j] * wrow[j];
        bc[n] = acc;
    }
}

// ---------------------------------------------------------------------------
// fp32 -> bf16 converts: z=0 ligand, z=1 prot (inter stays fp32)
// ---------------------------------------------------------------------------
__global__ __launch_bounds__(256)
void cvt2_kernel(const float* __restrict__ a, u16* __restrict__ da, int na,
                 const float* __restrict__ b, u16* __restrict__ db, int nb)
{
    const int zz = blockIdx.y;
    const float* s = zz ? b : a;
    u16* d = zz ? db : da;
    const int n = zz ? nb : na;
    const int i = (blockIdx.x * 256 + threadIdx.x) * 4;
    if (i >= n) return;
    const float4 v = *(const float4*)(s + i);
    u16x4 o;
    o.x = f2u(v.x); o.y = f2u(v.y); o.z = f2u(v.z); o.w = f2u(v.w);
    *(u16x4*)(d + i) = o;
}

// ---------------------------------------------------------------------------
extern "C" void kernel_launch(void* const* d_in, const int* in_sizes, int n_in,
                              void* d_out, int out_size, void* d_ws, size_t ws_size,
                              hipStream_t stream)
{
    (void)in_sizes; (void)n_in; (void)out_size; (void)ws_size;
    const float* ligand = (const float*)d_in[0];
    const float* prot   = (const float*)d_in[1];
    const float* inter  = (const float*)d_in[2];
    const float* Wl1 = (const float*)d_in[3];  const float* bl1 = (const float*)d_in[4];
    const float* Wl2 = (const float*)d_in[5];  const float* bl2 = (const float*)d_in[6];
    const float* Wp1 = (const float*)d_in[7];  const float* bp1 = (const float*)d_in[8];
    const float* Wp2 = (const float*)d_in[9];  const float* bp2 = (const float*)d_in[10];
    const float* W11 = (const float*)d_in[11]; const float* b11 = (const float*)d_in[12];
    const float* W12 = (const float*)d_in[13]; const float* b12 = (const float*)d_in[14];
    const float* W21 = (const float*)d_in[15]; const float* b21 = (const float*)d_in[16];
    const float* W22 = (const float*)d_in[17]; const float* b22 = (const float*)d_in[18];

    float* out0 = (float*)d_out;                    // [16,256,128]
    float* out1 = out0 + (size_t)16 * 256 * 128;    // [16,1024,128]

    u16* ws = (u16*)d_ws;
    size_t off = 0;
    auto alloc = [&](size_t n) { u16* p = ws + off; off += n; return p; };
    u16* ligb  = alloc(524288);    // bf16 ligand [4096,128]
    u16* protb = alloc(2097152);   // bf16 prot  [16384,128]
    u16* l1v   = alloc(4194304);   // [16,8,256,128]
    u16* l2t   = alloc(4194304);   // [16,8,128,256]  (head-T)
    u16* p1v   = alloc(16777216);  // [16,8,1024,128]
    u16* p2t   = alloc(16777216);  // [16,8,128,1024] (head-T)
    u16* attv  = alloc(33554432);  // [16,8,256,1024]
    u16* lig3  = alloc(4194304);   // [16,256,1024]
    u16* prot3 = alloc(16777216);  // [16,1024,1024]
    u16* Wl1t  = alloc(131072);    // [1024,128]
    u16* Wl2t  = alloc(131072);
    u16* Wp1t  = alloc(131072);
    u16* Wp2t  = alloc(131072);
    u16* W11t  = alloc(131072);    // [128,1024] = W11^T
    u16* W21t  = alloc(131072);    // [128,1024] = W21^T
    u16* W12t  = alloc(32768);     // [128,256]  = W12^T
    u16* W22t  = alloc(32768);     // [128,256]  = W22^T
    u16* WstL  = alloc(147456);    // [128,1152] combined lig weight
    u16* WstP  = alloc(147456);    // [128,1152] combined prot weight
    float* bcL = (float*)alloc(256);  // [128] f32
    float* bcP = (float*)alloc(256);  // [128] f32

    // input conversion (ligand, prot) -> bf16; inter stays fp32
    cvt2_kernel<<<dim3(2048, 2), 256, 0, stream>>>(
        ligand, ligb, 524288, prot, protb, 2097152);

    TPF8 tp;
    tp.t[0] = {Wl1, Wl1t, 128, 1024};
    tp.t[1] = {Wl2, Wl2t, 128, 1024};
    tp.t[2] = {Wp1, Wp1t, 128, 1024};
    tp.t[3] = {Wp2, Wp2t, 128, 1024};
    tp.t[4] = {W11, W11t, 1024, 128};
    tp.t[5] = {W21, W21t, 1024, 128};
    tp.t[6] = {W12, W12t, 256, 128};
    tp.t[7] = {W22, W22t, 256, 128};
    cvtw_kernel<<<dim3(32, 32, 8), 256, 0, stream>>>(tp);

    // combine W11@W12top / W21@W22top + residual halves + biases
    wcomb_kernel<<<dim3(128, 2), 256, 0, stream>>>(
        W11t, W12t, b11, b12, WstL, bcL,
        W21t, W22t, b21, b22, WstP, bcP);

    // all four projections in one dispatch
    proj_kernel<<<dim3(8, 320), 256, 0, stream>>>(
        ligb, protb, Wl1t, Wl2t, Wp1t, Wp2t,
        bl1, bl2, bp1, bp2, l1v, l2t, p1v, p2t);

    // attention scores + softmax (fp32 inter, proven shape)
    attn_kernel<<<dim3(16, 128), 256, 0, stream>>>(l1v, p1v, inter, attv);

    // both AV GEMMs in one dispatch (conflict-free prot transpose staging)
    av_kernel<<<dim3(640), 512, 0, stream>>>(attv, p2t, l2t, lig3, prot3);

    // both fused finals in one dispatch
    finals_kernel<<<dim3(1, 160), 256, 0, stream>>>(
        lig3, ligb, WstL, bcL, out0,
        prot3, protb, WstP, bcP, out1);
}